// Round 1
// baseline (9571.201 us; speedup 1.0000x reference)
//
#include <hip/hip_runtime.h>
#include <math.h>

#define DM    1024
#define NH1   16
#define HDIM1 64
#define NH2   8
#define HDIM2 128
#define NE    8
#define CAPE  320
#define BATCH 8
#define SEQ   1024
#define NTOK  (BATCH*SEQ)        /* 8192 */
#define OUTN  ((long)NTOK*DM)    /* 8388608 */

// ---------------- GEMM: C[M,N] = A[M,K] @ B[K,N] (+bias) ----------------
// 64x64 tile, 256 threads, 4x4 microtile. M%64==0, N%64==0, K%16==0.
__global__ __launch_bounds__(256) void gemm_bias(
    const float* __restrict__ A, const float* __restrict__ B,
    const float* __restrict__ bias, float* __restrict__ C,
    int M, int N, int K)
{
    __shared__ float As[64][17];
    __shared__ float Bs[16][64];
    const int t  = threadIdx.x;
    const int tx = t & 15, ty = t >> 4;
    const int m0 = blockIdx.y * 64, n0 = blockIdx.x * 64;
    float acc[4][4] = {{0.f}};
    const int arow = t >> 2, acol = (t & 3) * 4;
    const int bkk  = t >> 4, bnn  = (t & 15) * 4;
    for (int kb = 0; kb < K; kb += 16) {
        float4 a4 = *(const float4*)&A[(long)(m0 + arow) * K + kb + acol];
        As[arow][acol+0] = a4.x; As[arow][acol+1] = a4.y;
        As[arow][acol+2] = a4.z; As[arow][acol+3] = a4.w;
        *(float4*)&Bs[bkk][bnn] = *(const float4*)&B[(long)(kb + bkk) * N + n0 + bnn];
        __syncthreads();
        #pragma unroll
        for (int kk = 0; kk < 16; ++kk) {
            float av[4];
            #pragma unroll
            for (int i = 0; i < 4; ++i) av[i] = As[ty*4+i][kk];
            float4 b4 = *(const float4*)&Bs[kk][tx*4];
            float bv[4] = {b4.x, b4.y, b4.z, b4.w};
            #pragma unroll
            for (int i = 0; i < 4; ++i)
                #pragma unroll
                for (int j = 0; j < 4; ++j)
                    acc[i][j] += av[i] * bv[j];
        }
        __syncthreads();
    }
    float badd[4] = {0.f, 0.f, 0.f, 0.f};
    if (bias) {
        badd[0] = bias[n0+tx*4+0]; badd[1] = bias[n0+tx*4+1];
        badd[2] = bias[n0+tx*4+2]; badd[3] = bias[n0+tx*4+3];
    }
    #pragma unroll
    for (int i = 0; i < 4; ++i) {
        float4 o4;
        o4.x = acc[i][0]+badd[0]; o4.y = acc[i][1]+badd[1];
        o4.z = acc[i][2]+badd[2]; o4.w = acc[i][3]+badd[3];
        *(float4*)&C[(long)(m0+ty*4+i)*N + n0 + tx*4] = o4;
    }
}

// ---------------- Flash attention (online softmax), head-major layout ----
// Q/K/V/O are [batch, rows, DM] with head h at columns h*HD.. ; grid:
// x = q-tile (16 rows), y = head, z = batch.
template<int HD, int KT>
__global__ __launch_bounds__(256) void flash_attn(
    const float* __restrict__ Q, const float* __restrict__ K,
    const float* __restrict__ V, float* __restrict__ O,
    int rows, float scale)
{
    constexpr int QT  = 16;
    constexpr int DPT = HD / 16;   // d-columns per thread
    constexpr int SPT = KT / 16;   // scores per thread
    __shared__ float qs[QT][HD+1];
    __shared__ float ks[KT][HD+1];
    __shared__ float vs[KT][HD+1];
    __shared__ float sc[QT][KT+1];
    __shared__ float mrow[QT], lrow[QT], arow_[QT];
    const int t   = threadIdx.x;
    const int qi  = t >> 4, l16 = t & 15;
    const int q0  = blockIdx.x * QT;
    const long base = (long)blockIdx.z * rows * DM + (long)blockIdx.y * HD;

    #pragma unroll
    for (int r = 0; r < (QT*HD)/1024; ++r) {
        int idx = (t + r*256) * 4;
        int row = idx / HD, col = idx % HD;
        float4 v4 = *(const float4*)&Q[base + (long)(q0+row)*DM + col];
        qs[row][col+0]=v4.x; qs[row][col+1]=v4.y; qs[row][col+2]=v4.z; qs[row][col+3]=v4.w;
    }
    if (t < QT) { mrow[t] = -1e30f; lrow[t] = 0.f; }
    float acc[DPT];
    #pragma unroll
    for (int i = 0; i < DPT; ++i) acc[i] = 0.f;
    __syncthreads();

    for (int k0 = 0; k0 < rows; k0 += KT) {
        #pragma unroll
        for (int r = 0; r < (KT*HD)/1024; ++r) {
            int idx = (t + r*256) * 4;
            int j = idx / HD, col = idx % HD;
            float4 kv = *(const float4*)&K[base + (long)(k0+j)*DM + col];
            ks[j][col+0]=kv.x; ks[j][col+1]=kv.y; ks[j][col+2]=kv.z; ks[j][col+3]=kv.w;
            float4 vv = *(const float4*)&V[base + (long)(k0+j)*DM + col];
            vs[j][col+0]=vv.x; vs[j][col+1]=vv.y; vs[j][col+2]=vv.z; vs[j][col+3]=vv.w;
        }
        __syncthreads();
        {   // scores: each thread computes SPT scores for row qi
            float sacc[SPT];
            #pragma unroll
            for (int s = 0; s < SPT; ++s) sacc[s] = 0.f;
            const int jb = l16 * SPT;
            #pragma unroll 8
            for (int dd = 0; dd < HD; ++dd) {
                float qv = qs[qi][dd];
                #pragma unroll
                for (int s = 0; s < SPT; ++s) sacc[s] += qv * ks[jb+s][dd];
            }
            #pragma unroll
            for (int s = 0; s < SPT; ++s) sc[qi][jb+s] = sacc[s] * scale;
        }
        __syncthreads();
        if (t < QT) {   // online softmax per row
            float mold = mrow[t], mx = mold;
            for (int j = 0; j < KT; ++j) mx = fmaxf(mx, sc[t][j]);
            float alpha = __expf(mold - mx);
            float sum = 0.f;
            for (int j = 0; j < KT; ++j) { float p = __expf(sc[t][j]-mx); sc[t][j]=p; sum+=p; }
            mrow[t] = mx; lrow[t] = lrow[t]*alpha + sum; arow_[t] = alpha;
        }
        __syncthreads();
        float alpha = arow_[qi];
        #pragma unroll
        for (int i = 0; i < DPT; ++i) acc[i] *= alpha;
        const int db = l16 * DPT;
        for (int j = 0; j < KT; ++j) {
            float p = sc[qi][j];
            #pragma unroll
            for (int i = 0; i < DPT; ++i) acc[i] += p * vs[j][db+i];
        }
        __syncthreads();
    }
    float linv = 1.f / lrow[qi];
    long orow = base + (long)(q0+qi)*DM + l16*DPT;
    #pragma unroll
    for (int i = 0; i < DPT; i += 4) {
        float4 o4 = {acc[i]*linv, acc[i+1]*linv, acc[i+2]*linv, acc[i+3]*linv};
        *(float4*)&O[orow + i] = o4;
    }
}

// ---------------- Residual + LayerNorm: Y = LN(X + R) -------------------
__global__ __launch_bounds__(256) void ln_residual(
    const float* __restrict__ X, const float* __restrict__ R,
    const float* __restrict__ gam, const float* __restrict__ bet,
    float* __restrict__ Y)
{
    const long row = blockIdx.x;
    const int t = threadIdx.x;
    float4 xv = *(const float4*)&X[row*DM + t*4];
    float4 rv = *(const float4*)&R[row*DM + t*4];
    float v0=xv.x+rv.x, v1=xv.y+rv.y, v2=xv.z+rv.z, v3=xv.w+rv.w;
    float s  = v0+v1+v2+v3;
    float s2 = v0*v0+v1*v1+v2*v2+v3*v3;
    #pragma unroll
    for (int off = 32; off > 0; off >>= 1) {
        s  += __shfl_down(s,  off, 64);
        s2 += __shfl_down(s2, off, 64);
    }
    __shared__ float red[8];
    __shared__ float mv[2];
    const int wid = t >> 6;
    if ((t & 63) == 0) { red[wid] = s; red[4+wid] = s2; }
    __syncthreads();
    if (t == 0) {
        float S  = red[0]+red[1]+red[2]+red[3];
        float S2 = red[4]+red[5]+red[6]+red[7];
        float mean = S * (1.f/DM);
        float var  = S2 * (1.f/DM) - mean*mean;
        mv[0] = mean; mv[1] = rsqrtf(var + 1e-5f);
    }
    __syncthreads();
    float mean = mv[0], inv = mv[1];
    float4 g4 = *(const float4*)&gam[t*4];
    float4 b4 = *(const float4*)&bet[t*4];
    float4 o4;
    o4.x = (v0-mean)*inv*g4.x + b4.x;
    o4.y = (v1-mean)*inv*g4.y + b4.y;
    o4.z = (v2-mean)*inv*g4.z + b4.z;
    o4.w = (v3-mean)*inv*g4.w + b4.w;
    *(float4*)&Y[row*DM + t*4] = o4;
}

// ---------------- Gate: logits, softmax, top-2, loss accumulators -------
__global__ __launch_bounds__(64) void gate_kernel(
    const float* __restrict__ X1, const float* __restrict__ gW,
    int* __restrict__ e1, int* __restrict__ e2,
    float* __restrict__ g1, float* __restrict__ g2,
    float* __restrict__ accum)
{
    const long row = blockIdx.x;
    const int l = threadIdx.x;
    const float* x = X1 + row*DM;
    float part[8];
    #pragma unroll
    for (int e = 0; e < 8; ++e) part[e] = 0.f;
    for (int i = l; i < DM; i += 64) {
        float xv = x[i];
        float4 w0 = *(const float4*)&gW[i*8];
        float4 w1 = *(const float4*)&gW[i*8+4];
        part[0]+=xv*w0.x; part[1]+=xv*w0.y; part[2]+=xv*w0.z; part[3]+=xv*w0.w;
        part[4]+=xv*w1.x; part[5]+=xv*w1.y; part[6]+=xv*w1.z; part[7]+=xv*w1.w;
    }
    #pragma unroll
    for (int e = 0; e < 8; ++e) {
        float v = part[e];
        #pragma unroll
        for (int off = 32; off > 0; off >>= 1) v += __shfl_down(v, off, 64);
        part[e] = v;
    }
    if (l == 0) {
        float mx = part[0];
        #pragma unroll
        for (int e = 1; e < 8; ++e) mx = fmaxf(mx, part[e]);
        float p[8]; float sum = 0.f;
        #pragma unroll
        for (int e = 0; e < 8; ++e) { p[e] = expf(part[e]-mx); sum += p[e]; }
        float lse = mx + logf(sum);
        float isum = 1.f/sum;
        #pragma unroll
        for (int e = 0; e < 8; ++e) p[e] *= isum;
        int b1 = 0;
        #pragma unroll
        for (int e = 1; e < 8; ++e) if (p[e] > p[b1]) b1 = e;   // strict > => lowest-index tie-break
        int b2 = (b1 == 0) ? 1 : 0;
        #pragma unroll
        for (int e = 0; e < 8; ++e) if (e != b1 && e != b2 && p[e] > p[b2]) b2 = e;
        e1[row] = b1; e2[row] = b2; g1[row] = p[b1]; g2[row] = p[b2];
        atomicAdd(&accum[0], lse*lse);
        atomicAdd(&accum[9+b1], 1.0f);
        #pragma unroll
        for (int e = 0; e < 8; ++e) atomicAdd(&accum[1+e], p[e]);
    }
}

// ---------------- Routing scan: exclusive prefix per (batch, expert) ----
__global__ __launch_bounds__(64) void route_scan(
    const int* __restrict__ e1, const int* __restrict__ e2,
    const float* __restrict__ g2,
    int* __restrict__ pos1, int* __restrict__ keep1,
    int* __restrict__ pos2, int* __restrict__ keep2,
    int* __restrict__ slotmap)
{
    const int b = blockIdx.x;
    const int l = threadIdx.x;
    __shared__ int cnt[8];
    if (l < 8) cnt[l] = 0;
    __syncthreads();
    for (int slot = 0; slot < 2; ++slot) {
        const int* eArr = slot ? e2 : e1;
        for (int c = 0; c < SEQ/64; ++c) {
            const int tk = b*SEQ + c*64 + l;
            const int e = eArr[tk];
            const bool valid = slot ? (g2[tk] > 0.2f) : true;
            unsigned long long mymask = 0ull; int addmine = 0;
            #pragma unroll
            for (int ee = 0; ee < 8; ++ee) {
                unsigned long long bm = __ballot(valid && (e == ee));
                if (e == ee) mymask = bm;
                if (l == ee) addmine = (int)__popcll(bm);
            }
            const int p  = cnt[e] + (int)__popcll(mymask & ((1ull << l) - 1ull));
            const int kp = (valid && p < CAPE) ? 1 : 0;
            const int pc = p < CAPE ? p : (CAPE-1);
            if (slot == 0) { pos1[tk] = pc; keep1[tk] = kp; }
            else           { pos2[tk] = pc; keep2[tk] = kp; }
            if (kp) slotmap[(e*BATCH + b)*CAPE + pc] = tk;
            __syncthreads();
            if (l < 8) cnt[l] += addmine;
            __syncthreads();
        }
    }
}

// ---------------- Gather expert input (zeros for empty slots) -----------
__global__ __launch_bounds__(256) void gather_expert(
    const float* __restrict__ X1, const int* __restrict__ slotmap,
    float* __restrict__ Ein, int e)
{
    const int slot = blockIdx.x;              // b*CAPE + p
    const int t = threadIdx.x;
    const int tok = slotmap[e*(BATCH*CAPE) + slot];
    float4 v4 = make_float4(0.f, 0.f, 0.f, 0.f);
    if (tok >= 0) v4 = *(const float4*)&X1[(long)tok*DM + t*4];
    *(float4*)&Ein[(long)slot*DM + t*4] = v4;
}

// ---------------- Scatter expert output back, weighted by gate ----------
__global__ __launch_bounds__(256) void scatter_combine(
    const float* __restrict__ Eout, float* __restrict__ Y,
    const int* __restrict__ e1, const int* __restrict__ pos1,
    const int* __restrict__ keep1, const float* __restrict__ g1,
    const int* __restrict__ e2, const int* __restrict__ pos2,
    const int* __restrict__ keep2, const float* __restrict__ g2,
    int e)
{
    const long row = blockIdx.x;
    const int b = (int)(row >> 10);
    const int t = threadIdx.x;
    float w; long src;
    if (e1[row] == e && keep1[row])      { w = g1[row]; src = ((long)b*CAPE + pos1[row])*DM; }
    else if (e2[row] == e && keep2[row]) { w = g2[row]; src = ((long)b*CAPE + pos2[row])*DM; }
    else return;
    float4 ev = *(const float4*)&Eout[src + t*4];
    float4 yv = *(float4*)&Y[row*DM + t*4];
    yv.x += w*ev.x; yv.y += w*ev.y; yv.z += w*ev.z; yv.w += w*ev.w;
    *(float4*)&Y[row*DM + t*4] = yv;
}

// ---------------- Loss scalars ------------------------------------------
__global__ void finalize_loss(const float* __restrict__ accum, float* __restrict__ out)
{
    float z = accum[0] * (1.0f/NTOK);
    float s = 0.f;
    for (int e = 0; e < 8; ++e)
        s += (accum[1+e] * (1.0f/NTOK)) * (accum[9+e] * (1.0f/NTOK));
    float bal = 0.01f * 8.0f * s;
    float zl  = 0.001f * z;
    out[OUTN]   = bal + zl;
    out[OUTN+1] = bal;
    out[OUTN+2] = zl;
}

extern "C" void kernel_launch(void* const* d_in, const int* in_sizes, int n_in,
                              void* d_out, int out_size, void* d_ws, size_t ws_size,
                              hipStream_t stream)
{
    (void)in_sizes; (void)n_in; (void)out_size; (void)ws_size;
    const float* x    = (const float*)d_in[0];
    const float* Wq   = (const float*)d_in[1];
    const float* Wk   = (const float*)d_in[2];
    const float* Wv   = (const float*)d_in[3];
    const float* Wo   = (const float*)d_in[4];
    const float* bq   = (const float*)d_in[5];
    const float* bk   = (const float*)d_in[6];
    const float* bv   = (const float*)d_in[7];
    const float* bo   = (const float*)d_in[8];
    const float* ln1g = (const float*)d_in[9];
    const float* ln1b = (const float*)d_in[10];
    const float* ln2g = (const float*)d_in[11];
    const float* ln2b = (const float*)d_in[12];
    const float* gW   = (const float*)d_in[13];
    const float* eWq  = (const float*)d_in[14];
    const float* eWk  = (const float*)d_in[15];
    const float* eWv  = (const float*)d_in[16];
    const float* eWo  = (const float*)d_in[17];
    float* out = (float*)d_out;

    float* ws = (float*)d_ws;
    const long NBIG = 8388608;                // one [8192,1024] fp32 buffer
    float* W0 = ws;                           // q -> proj -> Ein/eq/ek
    float* W1 = ws + 1*NBIG;                  // k -> ev/eo/eout
    float* W2 = ws + 2*NBIG;                  // v -> x1
    float* W3 = ws + 3*NBIG;                  // o -> y accumulator
    int*   e1i   = (int*)(ws + 4*NBIG);
    int*   e2i   = e1i + NTOK;
    int*   pos1  = e1i + 2*NTOK;
    int*   pos2  = e1i + 3*NTOK;
    int*   keep1 = e1i + 4*NTOK;
    int*   keep2 = e1i + 5*NTOK;
    int*   slotmap = e1i + 6*NTOK;            // NE*BATCH*CAPE = 20480
    float* g1f   = (float*)(e1i + 6*NTOK + NE*BATCH*CAPE);
    float* g2f   = g1f + NTOK;
    float* accum = g2f + NTOK;                // 17 floats: z, P[8], f[8]

    dim3 blk(256);
    dim3 gmain(DM/64, NTOK/64);

    // ---- stage 1: MHA + LN1 ----
    gemm_bias<<<gmain, blk, 0, stream>>>(x, Wq, bq, W0, NTOK, DM, DM);
    gemm_bias<<<gmain, blk, 0, stream>>>(x, Wk, bk, W1, NTOK, DM, DM);
    gemm_bias<<<gmain, blk, 0, stream>>>(x, Wv, bv, W2, NTOK, DM, DM);
    flash_attn<HDIM1, 64><<<dim3(SEQ/16, NH1, BATCH), blk, 0, stream>>>(W0, W1, W2, W3, SEQ, 0.125f);
    gemm_bias<<<gmain, blk, 0, stream>>>(W3, Wo, bo, W0, NTOK, DM, DM);
    ln_residual<<<NTOK, blk, 0, stream>>>(x, W0, ln1g, ln1b, W2);   // W2 = x1

    // ---- gate + routing ----
    hipMemsetAsync(accum, 0, 17*sizeof(float), stream);
    hipMemsetAsync(slotmap, 0xFF, NE*BATCH*CAPE*sizeof(int), stream);  // -1
    gate_kernel<<<NTOK, dim3(64), 0, stream>>>(W2, gW, e1i, e2i, g1f, g2f, accum);
    route_scan<<<BATCH, dim3(64), 0, stream>>>(e1i, e2i, g2f, pos1, keep1, pos2, keep2, slotmap);
    hipMemsetAsync(W3, 0, NBIG*sizeof(float), stream);              // W3 = y = 0

    // ---- experts (chunked to bound workspace) ----
    const long EC = (long)BATCH*CAPE*DM;      // 2,621,440 floats per expert tensor
    for (int e = 0; e < NE; ++e) {
        float* Ein  = W0;
        float* eq   = W0 + EC;
        float* ek   = W0 + 2*EC;
        float* ev   = W1;
        float* eo   = W1 + EC;
        float* eout = W1 + 2*EC;
        gather_expert<<<BATCH*CAPE, blk, 0, stream>>>(W2, slotmap, Ein, e);
        dim3 ge(DM/64, (BATCH*CAPE)/64);
        gemm_bias<<<ge, blk, 0, stream>>>(Ein, eWq + (long)e*DM*DM, nullptr, eq, BATCH*CAPE, DM, DM);
        gemm_bias<<<ge, blk, 0, stream>>>(Ein, eWk + (long)e*DM*DM, nullptr, ek, BATCH*CAPE, DM, DM);
        gemm_bias<<<ge, blk, 0, stream>>>(Ein, eWv + (long)e*DM*DM, nullptr, ev, BATCH*CAPE, DM, DM);
        flash_attn<HDIM2, 32><<<dim3(CAPE/16, NH2, BATCH), blk, 0, stream>>>(eq, ek, ev, eo, CAPE, 0.088388347648318447f);
        gemm_bias<<<ge, blk, 0, stream>>>(eo, eWo + (long)e*DM*DM, nullptr, eout, BATCH*CAPE, DM, DM);
        scatter_combine<<<NTOK, blk, 0, stream>>>(eout, W3, e1i, pos1, keep1, g1f,
                                                  e2i, pos2, keep2, g2f, e);
    }

    // ---- final LN + losses ----
    ln_residual<<<NTOK, blk, 0, stream>>>(W2, W3, ln2g, ln2b, out);
    finalize_loss<<<1, 1, 0, stream>>>(accum, out);
}

// Round 2
// 6869.365 us; speedup vs baseline: 1.3933x; 1.3933x over previous
//
#include <hip/hip_runtime.h>
#include <hip/hip_bf16.h>
#include <math.h>

#define DM    1024
#define NH1   16
#define HDIM1 64
#define NH2   8
#define HDIM2 128
#define NE    8
#define CAPE  320
#define BATCH 8
#define SEQ   1024
#define NTOK  (BATCH*SEQ)        /* 8192 */
#define OUTN  ((long)NTOK*DM)    /* 8388608 */

typedef short bf16x8 __attribute__((ext_vector_type(8)));
typedef float f32x4  __attribute__((ext_vector_type(4)));

__device__ __forceinline__ unsigned short f2bf(float f) {
    __hip_bfloat16 h = __float2bfloat16(f);
    return *reinterpret_cast<unsigned short*>(&h);
}

__device__ __forceinline__ void async16(const void* g, void* lds) {
    __builtin_amdgcn_global_load_lds(
        (const __attribute__((address_space(1))) unsigned int*)g,
        (__attribute__((address_space(3))) unsigned int*)lds, 16, 0, 0);
}

// ---------------- bf16 MFMA GEMM: C[M,N] = A[M,K]bf16 @ B^T[N,K]bf16 (+bias) ----
// 128x128 tile, BK=32, 256 threads (4 waves, 2x2 wave grid, 4x4 MFMA tiles/wave).
__global__ __launch_bounds__(256) void gemm_bt(
    const unsigned short* __restrict__ A, const unsigned short* __restrict__ Bt,
    const float* __restrict__ bias, float* __restrict__ C,
    int M, int N, int K)
{
    __shared__ short ldsA[128*32];
    __shared__ short ldsB[128*32];
    const int t    = threadIdx.x;
    const int lane = t & 63, w = t >> 6;
    const int wr = w >> 1, wc = w & 1;        // 2x2 wave grid
    const int m0 = blockIdx.y * 128, n0 = blockIdx.x * 128;
    const int lq = lane >> 4, lm = lane & 15; // MFMA quad / row-col within 16
    // staging lane map: 4 lanes per row (8 bf16 = 16 B each)
    const int srow = w*16 + (lane >> 2);
    const int skc  = (lane & 3) * 8;

    f32x4 acc[4][4];
    #pragma unroll
    for (int i = 0; i < 4; ++i)
        #pragma unroll
        for (int j = 0; j < 4; ++j) acc[i][j] = (f32x4){0.f,0.f,0.f,0.f};

    for (int kb = 0; kb < K; kb += 32) {
        #pragma unroll
        for (int p = 0; p < 2; ++p) {
            async16(A  + (size_t)(m0 + srow + p*64)*K + kb + skc,
                    &ldsA[(w*16 + p*64)*32]);
            async16(Bt + (size_t)(n0 + srow + p*64)*K + kb + skc,
                    &ldsB[(w*16 + p*64)*32]);
        }
        __syncthreads();
        bf16x8 aF[4], bF[4];
        #pragma unroll
        for (int i = 0; i < 4; ++i)
            aF[i] = *(const bf16x8*)&ldsA[(wr*64 + i*16 + lm)*32 + lq*8];
        #pragma unroll
        for (int j = 0; j < 4; ++j)
            bF[j] = *(const bf16x8*)&ldsB[(wc*64 + j*16 + lm)*32 + lq*8];
        #pragma unroll
        for (int i = 0; i < 4; ++i)
            #pragma unroll
            for (int j = 0; j < 4; ++j)
                acc[i][j] = __builtin_amdgcn_mfma_f32_16x16x32_bf16(aF[i], bF[j], acc[i][j], 0, 0, 0);
        __syncthreads();
    }
    #pragma unroll
    for (int j = 0; j < 4; ++j) {
        const int gcol = n0 + wc*64 + j*16 + lm;
        const float badd = bias ? bias[gcol] : 0.f;
        #pragma unroll
        for (int i = 0; i < 4; ++i) {
            const int grow = m0 + wr*64 + i*16 + lq*4;
            #pragma unroll
            for (int r = 0; r < 4; ++r)
                C[(size_t)(grow + r)*N + gcol] = acc[i][j][r] + badd;
        }
    }
}

// ---------------- weight transpose + fp32->bf16: dst[n][k] = bf16(src[k][n]) ----
__global__ __launch_bounds__(256) void transpose_bf16(
    const float* __restrict__ src, unsigned short* __restrict__ dst)
{
    __shared__ float tile[32][33];
    const long mb = (long)blockIdx.z * (1024l*1024l);
    const int tx = threadIdx.x & 31, ty = threadIdx.x >> 5;
    const int r0 = blockIdx.y * 32, c0 = blockIdx.x * 32;
    #pragma unroll
    for (int rr = ty; rr < 32; rr += 8)
        tile[rr][tx] = src[mb + (long)(r0+rr)*1024 + c0 + tx];
    __syncthreads();
    #pragma unroll
    for (int rr = ty; rr < 32; rr += 8)
        dst[mb + (long)(c0+rr)*1024 + r0 + tx] = f2bf(tile[tx][rr]);
}

// ---------------- flat fp32 -> bf16 convert ----------------------------
__global__ __launch_bounds__(256) void convert_bf16(
    const float* __restrict__ src, unsigned short* __restrict__ dst, long n)
{
    long i = ((long)blockIdx.x*256 + threadIdx.x)*4;
    if (i >= n) return;
    float4 v = *(const float4*)&src[i];
    ushort4 o = { f2bf(v.x), f2bf(v.y), f2bf(v.z), f2bf(v.w) };
    *(ushort4*)&dst[i] = o;
}

// ---------------- Flash attention (fp32, unchanged from R1) ------------
template<int HD, int KT>
__global__ __launch_bounds__(256) void flash_attn(
    const float* __restrict__ Q, const float* __restrict__ K,
    const float* __restrict__ V, float* __restrict__ O,
    int rows, float scale)
{
    constexpr int QT  = 16;
    constexpr int DPT = HD / 16;
    constexpr int SPT = KT / 16;
    __shared__ float qs[QT][HD+1];
    __shared__ float ks[KT][HD+1];
    __shared__ float vs[KT][HD+1];
    __shared__ float sc[QT][KT+1];
    __shared__ float mrow[QT], lrow[QT], arow_[QT];
    const int t   = threadIdx.x;
    const int qi  = t >> 4, l16 = t & 15;
    const int q0  = blockIdx.x * QT;
    const long base = (long)blockIdx.z * rows * DM + (long)blockIdx.y * HD;

    #pragma unroll
    for (int r = 0; r < (QT*HD)/1024; ++r) {
        int idx = (t + r*256) * 4;
        int row = idx / HD, col = idx % HD;
        float4 v4 = *(const float4*)&Q[base + (long)(q0+row)*DM + col];
        qs[row][col+0]=v4.x; qs[row][col+1]=v4.y; qs[row][col+2]=v4.z; qs[row][col+3]=v4.w;
    }
    if (t < QT) { mrow[t] = -1e30f; lrow[t] = 0.f; }
    float acc[DPT];
    #pragma unroll
    for (int i = 0; i < DPT; ++i) acc[i] = 0.f;
    __syncthreads();

    for (int k0 = 0; k0 < rows; k0 += KT) {
        #pragma unroll
        for (int r = 0; r < (KT*HD)/1024; ++r) {
            int idx = (t + r*256) * 4;
            int j = idx / HD, col = idx % HD;
            float4 kv = *(const float4*)&K[base + (long)(k0+j)*DM + col];
            ks[j][col+0]=kv.x; ks[j][col+1]=kv.y; ks[j][col+2]=kv.z; ks[j][col+3]=kv.w;
            float4 vv = *(const float4*)&V[base + (long)(k0+j)*DM + col];
            vs[j][col+0]=vv.x; vs[j][col+1]=vv.y; vs[j][col+2]=vv.z; vs[j][col+3]=vv.w;
        }
        __syncthreads();
        {
            float sacc[SPT];
            #pragma unroll
            for (int s = 0; s < SPT; ++s) sacc[s] = 0.f;
            const int jb = l16 * SPT;
            #pragma unroll 8
            for (int dd = 0; dd < HD; ++dd) {
                float qv = qs[qi][dd];
                #pragma unroll
                for (int s = 0; s < SPT; ++s) sacc[s] += qv * ks[jb+s][dd];
            }
            #pragma unroll
            for (int s = 0; s < SPT; ++s) sc[qi][jb+s] = sacc[s] * scale;
        }
        __syncthreads();
        if (t < QT) {
            float mold = mrow[t], mx = mold;
            for (int j = 0; j < KT; ++j) mx = fmaxf(mx, sc[t][j]);
            float alpha = __expf(mold - mx);
            float sum = 0.f;
            for (int j = 0; j < KT; ++j) { float p = __expf(sc[t][j]-mx); sc[t][j]=p; sum+=p; }
            mrow[t] = mx; lrow[t] = lrow[t]*alpha + sum; arow_[t] = alpha;
        }
        __syncthreads();
        float alpha = arow_[qi];
        #pragma unroll
        for (int i = 0; i < DPT; ++i) acc[i] *= alpha;
        const int db = l16 * DPT;
        for (int j = 0; j < KT; ++j) {
            float p = sc[qi][j];
            #pragma unroll
            for (int i = 0; i < DPT; ++i) acc[i] += p * vs[j][db+i];
        }
        __syncthreads();
    }
    float linv = 1.f / lrow[qi];
    long orow = base + (long)(q0+qi)*DM + l16*DPT;
    #pragma unroll
    for (int i = 0; i < DPT; i += 4) {
        float4 o4 = {acc[i]*linv, acc[i+1]*linv, acc[i+2]*linv, acc[i+3]*linv};
        *(float4*)&O[orow + i] = o4;
    }
}

// ---------------- Residual + LayerNorm ---------------------------------
__global__ __launch_bounds__(256) void ln_residual(
    const float* __restrict__ X, const float* __restrict__ R,
    const float* __restrict__ gam, const float* __restrict__ bet,
    float* __restrict__ Y)
{
    const long row = blockIdx.x;
    const int t = threadIdx.x;
    float4 xv = *(const float4*)&X[row*DM + t*4];
    float4 rv = *(const float4*)&R[row*DM + t*4];
    float v0=xv.x+rv.x, v1=xv.y+rv.y, v2=xv.z+rv.z, v3=xv.w+rv.w;
    float s  = v0+v1+v2+v3;
    float s2 = v0*v0+v1*v1+v2*v2+v3*v3;
    #pragma unroll
    for (int off = 32; off > 0; off >>= 1) {
        s  += __shfl_down(s,  off, 64);
        s2 += __shfl_down(s2, off, 64);
    }
    __shared__ float red[8];
    __shared__ float mv[2];
    const int wid = t >> 6;
    if ((t & 63) == 0) { red[wid] = s; red[4+wid] = s2; }
    __syncthreads();
    if (t == 0) {
        float S  = red[0]+red[1]+red[2]+red[3];
        float S2 = red[4]+red[5]+red[6]+red[7];
        float mean = S * (1.f/DM);
        float var  = S2 * (1.f/DM) - mean*mean;
        mv[0] = mean; mv[1] = rsqrtf(var + 1e-5f);
    }
    __syncthreads();
    float mean = mv[0], inv = mv[1];
    float4 g4 = *(const float4*)&gam[t*4];
    float4 b4 = *(const float4*)&bet[t*4];
    float4 o4;
    o4.x = (v0-mean)*inv*g4.x + b4.x;
    o4.y = (v1-mean)*inv*g4.y + b4.y;
    o4.z = (v2-mean)*inv*g4.z + b4.z;
    o4.w = (v3-mean)*inv*g4.w + b4.w;
    *(float4*)&Y[row*DM + t*4] = o4;
}

// ---------------- Gate ---------------------------------------------------
__global__ __launch_bounds__(64) void gate_kernel(
    const float* __restrict__ X1, const float* __restrict__ gW,
    int* __restrict__ e1, int* __restrict__ e2,
    float* __restrict__ g1, float* __restrict__ g2,
    float* __restrict__ accum)
{
    const long row = blockIdx.x;
    const int l = threadIdx.x;
    const float* x = X1 + row*DM;
    float part[8];
    #pragma unroll
    for (int e = 0; e < 8; ++e) part[e] = 0.f;
    for (int i = l; i < DM; i += 64) {
        float xv = x[i];
        float4 w0 = *(const float4*)&gW[i*8];
        float4 w1 = *(const float4*)&gW[i*8+4];
        part[0]+=xv*w0.x; part[1]+=xv*w0.y; part[2]+=xv*w0.z; part[3]+=xv*w0.w;
        part[4]+=xv*w1.x; part[5]+=xv*w1.y; part[6]+=xv*w1.z; part[7]+=xv*w1.w;
    }
    #pragma unroll
    for (int e = 0; e < 8; ++e) {
        float v = part[e];
        #pragma unroll
        for (int off = 32; off > 0; off >>= 1) v += __shfl_down(v, off, 64);
        part[e] = v;
    }
    if (l == 0) {
        float mx = part[0];
        #pragma unroll
        for (int e = 1; e < 8; ++e) mx = fmaxf(mx, part[e]);
        float p[8]; float sum = 0.f;
        #pragma unroll
        for (int e = 0; e < 8; ++e) { p[e] = expf(part[e]-mx); sum += p[e]; }
        float lse = mx + logf(sum);
        float isum = 1.f/sum;
        #pragma unroll
        for (int e = 0; e < 8; ++e) p[e] *= isum;
        int b1 = 0;
        #pragma unroll
        for (int e = 1; e < 8; ++e) if (p[e] > p[b1]) b1 = e;
        int b2 = (b1 == 0) ? 1 : 0;
        #pragma unroll
        for (int e = 0; e < 8; ++e) if (e != b1 && e != b2 && p[e] > p[b2]) b2 = e;
        e1[row] = b1; e2[row] = b2; g1[row] = p[b1]; g2[row] = p[b2];
        atomicAdd(&accum[0], lse*lse);
        atomicAdd(&accum[9+b1], 1.0f);
        #pragma unroll
        for (int e = 0; e < 8; ++e) atomicAdd(&accum[1+e], p[e]);
    }
}

// ---------------- Routing scan ------------------------------------------
__global__ __launch_bounds__(64) void route_scan(
    const int* __restrict__ e1, const int* __restrict__ e2,
    const float* __restrict__ g2,
    int* __restrict__ pos1, int* __restrict__ keep1,
    int* __restrict__ pos2, int* __restrict__ keep2,
    int* __restrict__ slotmap)
{
    const int b = blockIdx.x;
    const int l = threadIdx.x;
    __shared__ int cnt[8];
    if (l < 8) cnt[l] = 0;
    __syncthreads();
    for (int slot = 0; slot < 2; ++slot) {
        const int* eArr = slot ? e2 : e1;
        for (int c = 0; c < SEQ/64; ++c) {
            const int tk = b*SEQ + c*64 + l;
            const int e = eArr[tk];
            const bool valid = slot ? (g2[tk] > 0.2f) : true;
            unsigned long long mymask = 0ull; int addmine = 0;
            #pragma unroll
            for (int ee = 0; ee < 8; ++ee) {
                unsigned long long bm = __ballot(valid && (e == ee));
                if (e == ee) mymask = bm;
                if (l == ee) addmine = (int)__popcll(bm);
            }
            const int p  = cnt[e] + (int)__popcll(mymask & ((1ull << l) - 1ull));
            const int kp = (valid && p < CAPE) ? 1 : 0;
            const int pc = p < CAPE ? p : (CAPE-1);
            if (slot == 0) { pos1[tk] = pc; keep1[tk] = kp; }
            else           { pos2[tk] = pc; keep2[tk] = kp; }
            if (kp) slotmap[(e*BATCH + b)*CAPE + pc] = tk;
            __syncthreads();
            if (l < 8) cnt[l] += addmine;
            __syncthreads();
        }
    }
}

// ---------------- Gather expert input -> bf16 ---------------------------
__global__ __launch_bounds__(256) void gather_expert(
    const float* __restrict__ X1, const int* __restrict__ slotmap,
    unsigned short* __restrict__ Ein, int e)
{
    const int slot = blockIdx.x;
    const int t = threadIdx.x;
    const int tok = slotmap[e*(BATCH*CAPE) + slot];
    float4 v4 = make_float4(0.f, 0.f, 0.f, 0.f);
    if (tok >= 0) v4 = *(const float4*)&X1[(long)tok*DM + t*4];
    ushort4 o = { f2bf(v4.x), f2bf(v4.y), f2bf(v4.z), f2bf(v4.w) };
    *(ushort4*)&Ein[(long)slot*DM + t*4] = o;
}

// ---------------- Scatter expert output ---------------------------------
__global__ __launch_bounds__(256) void scatter_combine(
    const float* __restrict__ Eout, float* __restrict__ Y,
    const int* __restrict__ e1, const int* __restrict__ pos1,
    const int* __restrict__ keep1, const float* __restrict__ g1,
    const int* __restrict__ e2, const int* __restrict__ pos2,
    const int* __restrict__ keep2, const float* __restrict__ g2,
    int e)
{
    const long row = blockIdx.x;
    const int b = (int)(row >> 10);
    const int t = threadIdx.x;
    float w; long src;
    if (e1[row] == e && keep1[row])      { w = g1[row]; src = ((long)b*CAPE + pos1[row])*DM; }
    else if (e2[row] == e && keep2[row]) { w = g2[row]; src = ((long)b*CAPE + pos2[row])*DM; }
    else return;
    float4 ev = *(const float4*)&Eout[src + t*4];
    float4 yv = *(float4*)&Y[row*DM + t*4];
    yv.x += w*ev.x; yv.y += w*ev.y; yv.z += w*ev.z; yv.w += w*ev.w;
    *(float4*)&Y[row*DM + t*4] = yv;
}

// ---------------- Loss scalars ------------------------------------------
__global__ void finalize_loss(const float* __restrict__ accum, float* __restrict__ out)
{
    float z = accum[0] * (1.0f/NTOK);
    float s = 0.f;
    for (int e = 0; e < 8; ++e)
        s += (accum[1+e] * (1.0f/NTOK)) * (accum[9+e] * (1.0f/NTOK));
    float bal = 0.01f * 8.0f * s;
    float zl  = 0.001f * z;
    out[OUTN]   = bal + zl;
    out[OUTN+1] = bal;
    out[OUTN+2] = zl;
}

extern "C" void kernel_launch(void* const* d_in, const int* in_sizes, int n_in,
                              void* d_out, int out_size, void* d_ws, size_t ws_size,
                              hipStream_t stream)
{
    (void)in_sizes; (void)n_in; (void)out_size; (void)ws_size;
    const float* x    = (const float*)d_in[0];
    const float* Wq   = (const float*)d_in[1];
    const float* Wk   = (const float*)d_in[2];
    const float* Wv   = (const float*)d_in[3];
    const float* Wo   = (const float*)d_in[4];
    const float* bq   = (const float*)d_in[5];
    const float* bk   = (const float*)d_in[6];
    const float* bv   = (const float*)d_in[7];
    const float* bo   = (const float*)d_in[8];
    const float* ln1g = (const float*)d_in[9];
    const float* ln1b = (const float*)d_in[10];
    const float* ln2g = (const float*)d_in[11];
    const float* ln2b = (const float*)d_in[12];
    const float* gW   = (const float*)d_in[13];
    const float* eWq  = (const float*)d_in[14];
    const float* eWk  = (const float*)d_in[15];
    const float* eWv  = (const float*)d_in[16];
    const float* eWo  = (const float*)d_in[17];
    float* out = (float*)d_out;

    char* ws = (char*)d_ws;
    const long MATE = 1024l*1024l;              // elems per 1024x1024 matrix
    // bf16 transposed weights: 36 matrices x 2 MB = 72 MB
    unsigned short* WTq  = (unsigned short*)(ws);
    unsigned short* WTk  = WTq + 1*MATE;
    unsigned short* WTv  = WTq + 2*MATE;
    unsigned short* WTo  = WTq + 3*MATE;
    unsigned short* eWTq = WTq + 4*MATE;        // [8] matrices each
    unsigned short* eWTk = WTq + 12*MATE;
    unsigned short* eWTv = WTq + 20*MATE;
    unsigned short* eWTo = WTq + 28*MATE;
    char* p = ws + 36*MATE*2;                   // 75497472
    unsigned short* xb = (unsigned short*)p; p += OUTN*2;   // 16 MB (xb, later ob)
    float* Qf = (float*)p; p += OUTN*4;         // 32 MB
    float* Kf = (float*)p; p += OUTN*4;         // 32 MB  (later x1)
    float* Vf = (float*)p; p += OUTN*4;         // 32 MB  (later y)
    float* Of = (float*)p; p += OUTN*4;         // 32 MB  (later eq/ek/ev)
    int*   e1i   = (int*)p;
    int*   e2i   = e1i + NTOK;
    int*   pos1  = e1i + 2*NTOK;
    int*   pos2  = e1i + 3*NTOK;
    int*   keep1 = e1i + 4*NTOK;
    int*   keep2 = e1i + 5*NTOK;
    int*   slotmap = e1i + 6*NTOK;              // 20480 ints
    float* g1f   = (float*)(e1i + 6*NTOK + NE*BATCH*CAPE);
    float* g2f   = g1f + NTOK;
    float* accum = g2f + NTOK;                  // 17 floats

    // expert-loop scratch aliases
    const long ECE = (long)BATCH*CAPE*DM;       // 2,621,440 elems
    unsigned short* Einb = (unsigned short*)Qf;                 // 5 MB
    float* eo   = (float*)((char*)Qf + 5*1024*1024);            // 10 MB
    unsigned short* eob = (unsigned short*)((char*)Qf + 15*1024*1024); // 5 MB
    float* eout = (float*)((char*)Qf + 20*1024*1024);           // 10 MB
    float* eq = Of;
    float* ek = (float*)((char*)Of + 10*1024*1024);
    float* ev = (float*)((char*)Of + 20*1024*1024);

    dim3 blk(256);
    dim3 tgrid(32, 32, 1), tgrid8(32, 32, 8);

    // ---- weight prep (bf16 + transpose) ----
    transpose_bf16<<<tgrid,  blk, 0, stream>>>(Wq,  WTq);
    transpose_bf16<<<tgrid,  blk, 0, stream>>>(Wk,  WTk);
    transpose_bf16<<<tgrid,  blk, 0, stream>>>(Wv,  WTv);
    transpose_bf16<<<tgrid,  blk, 0, stream>>>(Wo,  WTo);
    transpose_bf16<<<tgrid8, blk, 0, stream>>>(eWq, eWTq);
    transpose_bf16<<<tgrid8, blk, 0, stream>>>(eWk, eWTk);
    transpose_bf16<<<tgrid8, blk, 0, stream>>>(eWv, eWTv);
    transpose_bf16<<<tgrid8, blk, 0, stream>>>(eWo, eWTo);
    convert_bf16<<<NTOK, blk, 0, stream>>>(x, xb, OUTN);

    // ---- stage 1: MHA + LN1 ----
    dim3 gmain(DM/128, NTOK/128);
    gemm_bt<<<gmain, blk, 0, stream>>>(xb, WTq, bq, Qf, NTOK, DM, DM);
    gemm_bt<<<gmain, blk, 0, stream>>>(xb, WTk, bk, Kf, NTOK, DM, DM);
    gemm_bt<<<gmain, blk, 0, stream>>>(xb, WTv, bv, Vf, NTOK, DM, DM);
    flash_attn<HDIM1, 64><<<dim3(SEQ/16, NH1, BATCH), blk, 0, stream>>>(Qf, Kf, Vf, Of, SEQ, 0.125f);
    convert_bf16<<<NTOK, blk, 0, stream>>>(Of, xb, OUTN);   // ob
    gemm_bt<<<gmain, blk, 0, stream>>>(xb, WTo, bo, Qf, NTOK, DM, DM);  // attn proj
    ln_residual<<<NTOK, blk, 0, stream>>>(x, Qf, ln1g, ln1b, Kf);       // Kf = x1

    // ---- gate + routing ----
    hipMemsetAsync(accum, 0, 17*sizeof(float), stream);
    hipMemsetAsync(slotmap, 0xFF, NE*BATCH*CAPE*sizeof(int), stream);
    gate_kernel<<<NTOK, dim3(64), 0, stream>>>(Kf, gW, e1i, e2i, g1f, g2f, accum);
    route_scan<<<BATCH, dim3(64), 0, stream>>>(e1i, e2i, g2f, pos1, keep1, pos2, keep2, slotmap);
    hipMemsetAsync(Vf, 0, OUTN*sizeof(float), stream);      // Vf = y = 0

    // ---- experts ----
    dim3 ge(DM/128, (BATCH*CAPE)/128);
    for (int e = 0; e < NE; ++e) {
        gather_expert<<<BATCH*CAPE, blk, 0, stream>>>(Kf, slotmap, Einb, e);
        gemm_bt<<<ge, blk, 0, stream>>>(Einb, eWTq + (long)e*MATE, nullptr, eq, BATCH*CAPE, DM, DM);
        gemm_bt<<<ge, blk, 0, stream>>>(Einb, eWTk + (long)e*MATE, nullptr, ek, BATCH*CAPE, DM, DM);
        gemm_bt<<<ge, blk, 0, stream>>>(Einb, eWTv + (long)e*MATE, nullptr, ev, BATCH*CAPE, DM, DM);
        flash_attn<HDIM2, 32><<<dim3(CAPE/16, NH2, BATCH), blk, 0, stream>>>(eq, ek, ev, eo, CAPE, 0.088388347648318447f);
        convert_bf16<<<(int)(ECE/1024), blk, 0, stream>>>(eo, eob, ECE);
        gemm_bt<<<ge, blk, 0, stream>>>(eob, eWTo + (long)e*MATE, nullptr, eout, BATCH*CAPE, DM, DM);
        scatter_combine<<<NTOK, blk, 0, stream>>>(eout, Vf, e1i, pos1, keep1, g1f,
                                                  e2i, pos2, keep2, g2f, e);
    }

    // ---- final LN + losses ----
    ln_residual<<<NTOK, blk, 0, stream>>>(Kf, Vf, ln2g, ln2b, out);
    finalize_loss<<<1, 1, 0, stream>>>(accum, out);
}

// Round 3
// 2968.491 us; speedup vs baseline: 3.2243x; 2.3141x over previous
//
#include <hip/hip_runtime.h>
#include <hip/hip_bf16.h>
#include <math.h>

#define DM    1024
#define NH1   16
#define HDIM1 64
#define NH2   8
#define HDIM2 128
#define NE    8
#define CAPE  320
#define BATCH 8
#define SEQ   1024
#define NTOK  (BATCH*SEQ)        /* 8192 */
#define OUTN  ((long)NTOK*DM)    /* 8388608 */

typedef short bf16x8 __attribute__((ext_vector_type(8)));
typedef float f32x4  __attribute__((ext_vector_type(4)));

__device__ __forceinline__ unsigned short f2bf(float f) {
    __hip_bfloat16 h = __float2bfloat16(f);
    return *reinterpret_cast<unsigned short*>(&h);
}

__device__ __forceinline__ void async16(const void* g, void* lds) {
    __builtin_amdgcn_global_load_lds(
        (const __attribute__((address_space(1))) unsigned int*)g,
        (__attribute__((address_space(3))) unsigned int*)lds, 16, 0, 0);
}

// ---------------- bf16 MFMA GEMM: C[M,N] = A[M,K]bf16 @ B^T[N,K]bf16 (+bias) ----
// 128x128 tile, BK=32, 256 threads (4 waves, 2x2 wave grid, 4x4 MFMA tiles/wave).
// OT = float (fp32 out) or unsigned short (bf16 out).
template<typename OT>
__global__ __launch_bounds__(256) void gemm_bt(
    const unsigned short* __restrict__ A, const unsigned short* __restrict__ Bt,
    const float* __restrict__ bias, OT* __restrict__ C,
    int M, int N, int K)
{
    __shared__ short ldsA[128*32];
    __shared__ short ldsB[128*32];
    const int t    = threadIdx.x;
    const int lane = t & 63, w = t >> 6;
    const int wr = w >> 1, wc = w & 1;
    const int m0 = blockIdx.y * 128, n0 = blockIdx.x * 128;
    const int lq = lane >> 4, lm = lane & 15;
    const int srow = w*16 + (lane >> 2);
    const int skc  = (lane & 3) * 8;

    f32x4 acc[4][4];
    #pragma unroll
    for (int i = 0; i < 4; ++i)
        #pragma unroll
        for (int j = 0; j < 4; ++j) acc[i][j] = (f32x4){0.f,0.f,0.f,0.f};

    for (int kb = 0; kb < K; kb += 32) {
        #pragma unroll
        for (int p = 0; p < 2; ++p) {
            async16(A  + (size_t)(m0 + srow + p*64)*K + kb + skc,
                    &ldsA[(w*16 + p*64)*32]);
            async16(Bt + (size_t)(n0 + srow + p*64)*K + kb + skc,
                    &ldsB[(w*16 + p*64)*32]);
        }
        __syncthreads();
        bf16x8 aF[4], bF[4];
        #pragma unroll
        for (int i = 0; i < 4; ++i)
            aF[i] = *(const bf16x8*)&ldsA[(wr*64 + i*16 + lm)*32 + lq*8];
        #pragma unroll
        for (int j = 0; j < 4; ++j)
            bF[j] = *(const bf16x8*)&ldsB[(wc*64 + j*16 + lm)*32 + lq*8];
        #pragma unroll
        for (int i = 0; i < 4; ++i)
            #pragma unroll
            for (int j = 0; j < 4; ++j)
                acc[i][j] = __builtin_amdgcn_mfma_f32_16x16x32_bf16(aF[i], bF[j], acc[i][j], 0, 0, 0);
        __syncthreads();
    }
    #pragma unroll
    for (int j = 0; j < 4; ++j) {
        const int gcol = n0 + wc*64 + j*16 + lm;
        const float badd = bias ? bias[gcol] : 0.f;
        #pragma unroll
        for (int i = 0; i < 4; ++i) {
            const int grow = m0 + wr*64 + i*16 + lq*4;
            #pragma unroll
            for (int r = 0; r < 4; ++r) {
                float v = acc[i][j][r] + badd;
                if constexpr (sizeof(OT) == 2)
                    C[(size_t)(grow + r)*N + gcol] = f2bf(v);
                else
                    C[(size_t)(grow + r)*N + gcol] = v;
            }
        }
    }
}

// ---------------- MFMA flash attention (bf16 in/out, fp32 softmax) ------
// One block = 64 query rows of one (batch, head). 4 waves, 16 q-rows each.
// KT=64 keys per iteration. Q/K row-major LDS (pad+8), V transposed with
// XOR-block swizzle so PV B-fragments are contiguous b128 reads.
template<int HD>
__global__ __launch_bounds__(256) void flash_mfma(
    const unsigned short* __restrict__ Q, const unsigned short* __restrict__ K,
    const unsigned short* __restrict__ V, unsigned short* __restrict__ O,
    int rows, float scale)
{
    constexpr int QT = 64, KT = 64;
    constexpr int PADQ = HD + 8;
    constexpr int NKT = HD / 32;      // MFMAs per 16x16 score tile
    constexpr int NDT = HD / 16;      // output d-tiles
    constexpr int CG  = HD / 8;       // 8-elem col groups per row
    constexpr int RPR = 256 / CG;     // rows staged per round
    __shared__ __align__(16) unsigned short qs[QT * PADQ];
    __shared__ __align__(16) unsigned short ks[KT * PADQ];
    __shared__ __align__(16) unsigned short vt[HD * KT];      // [d][j] swizzled
    __shared__ __align__(16) unsigned short pP[4][16 * 72];
    const int t = threadIdx.x, lane = t & 63, w = t >> 6;
    const int lm = lane & 15, quad = lane >> 4;
    const int q0 = blockIdx.x * QT;
    const long base = (long)blockIdx.z * rows * DM + (long)blockIdx.y * HD;
    const int srow = t / CG, scg = t % CG;

    #pragma unroll
    for (int r = 0; r < QT / RPR; ++r) {
        int row = srow + r * RPR;
        *(bf16x8*)&qs[row * PADQ + scg * 8] =
            *(const bf16x8*)&Q[base + (long)(q0 + row) * DM + scg * 8];
    }
    __syncthreads();
    bf16x8 aQ[NKT];
    #pragma unroll
    for (int kk = 0; kk < NKT; ++kk)
        aQ[kk] = *(const bf16x8*)&qs[(w * 16 + lm) * PADQ + kk * 32 + quad * 8];

    float m4[4], l4[4];
    #pragma unroll
    for (int r = 0; r < 4; ++r) { m4[r] = -1e30f; l4[r] = 0.f; }
    f32x4 aco[NDT];
    #pragma unroll
    for (int d = 0; d < NDT; ++d) aco[d] = (f32x4){0.f,0.f,0.f,0.f};

    for (int k0 = 0; k0 < rows; k0 += KT) {
        __syncthreads();
        #pragma unroll
        for (int r = 0; r < KT / RPR; ++r) {
            int row = srow + r * RPR;
            *(bf16x8*)&ks[row * PADQ + scg * 8] =
                *(const bf16x8*)&K[base + (long)(k0 + row) * DM + scg * 8];
            bf16x8 vv = *(const bf16x8*)&V[base + (long)(k0 + row) * DM + scg * 8];
            #pragma unroll
            for (int u = 0; u < 8; ++u) {
                int d = scg * 8 + u;
                vt[d * KT + ((row >> 3) ^ (d & 7)) * 8 + (row & 7)] = ((short*)&vv)[u];
            }
        }
        __syncthreads();
        // ---- scores: QK^T for 64 keys ----
        f32x4 sc[4];
        #pragma unroll
        for (int n = 0; n < 4; ++n) {
            f32x4 c = (f32x4){0.f,0.f,0.f,0.f};
            #pragma unroll
            for (int kk = 0; kk < NKT; ++kk) {
                bf16x8 bK = *(const bf16x8*)&ks[(n * 16 + lm) * PADQ + kk * 32 + quad * 8];
                c = __builtin_amdgcn_mfma_f32_16x16x32_bf16(aQ[kk], bK, c, 0, 0, 0);
            }
            #pragma unroll
            for (int r = 0; r < 4; ++r) c[r] *= scale;
            sc[n] = c;
        }
        // ---- online softmax (rows = quad*4+r, cols across 16 lanes of quad) ----
        float alpha[4];
        #pragma unroll
        for (int r = 0; r < 4; ++r) {
            float mx = fmaxf(fmaxf(sc[0][r], sc[1][r]), fmaxf(sc[2][r], sc[3][r]));
            #pragma unroll
            for (int off = 1; off < 16; off <<= 1)
                mx = fmaxf(mx, __shfl_xor(mx, off, 64));
            float mnew = fmaxf(m4[r], mx);
            alpha[r] = __expf(m4[r] - mnew);
            m4[r] = mnew;
            float s = 0.f;
            #pragma unroll
            for (int n = 0; n < 4; ++n) {
                float p = __expf(sc[n][r] - mnew);
                sc[n][r] = p; s += p;
            }
            #pragma unroll
            for (int off = 1; off < 16; off <<= 1)
                s += __shfl_xor(s, off, 64);
            l4[r] = l4[r] * alpha[r] + s;
        }
        // ---- P (C-layout) -> LDS -> A-layout ----
        #pragma unroll
        for (int n = 0; n < 4; ++n)
            #pragma unroll
            for (int r = 0; r < 4; ++r)
                pP[w][(quad * 4 + r) * 72 + n * 16 + lm] = f2bf(sc[n][r]);
        #pragma unroll
        for (int d = 0; d < NDT; ++d)
            #pragma unroll
            for (int r = 0; r < 4; ++r) aco[d][r] *= alpha[r];
        #pragma unroll
        for (int d = 0; d < NDT; ++d) {
            #pragma unroll
            for (int kk = 0; kk < 2; ++kk) {
                bf16x8 aP = *(const bf16x8*)&pP[w][lm * 72 + kk * 32 + quad * 8];
                int dd = d * 16 + lm;
                int jb = kk * 4 + quad;
                bf16x8 bV = *(const bf16x8*)&vt[dd * KT + ((jb ^ (dd & 7)) * 8)];
                aco[d] = __builtin_amdgcn_mfma_f32_16x16x32_bf16(aP, bV, aco[d], 0, 0, 0);
            }
        }
    }
    #pragma unroll
    for (int r = 0; r < 4; ++r) l4[r] = 1.f / l4[r];
    #pragma unroll
    for (int d = 0; d < NDT; ++d)
        #pragma unroll
        for (int r = 0; r < 4; ++r)
            O[base + (long)(q0 + w * 16 + quad * 4 + r) * DM + d * 16 + lm] =
                f2bf(aco[d][r] * l4[r]);
}

// ---------------- weight transpose + fp32->bf16 -------------------------
__global__ __launch_bounds__(256) void transpose_bf16(
    const float* __restrict__ src, unsigned short* __restrict__ dst)
{
    __shared__ float tile[32][33];
    const long mb = (long)blockIdx.z * (1024l*1024l);
    const int tx = threadIdx.x & 31, ty = threadIdx.x >> 5;
    const int r0 = blockIdx.y * 32, c0 = blockIdx.x * 32;
    #pragma unroll
    for (int rr = ty; rr < 32; rr += 8)
        tile[rr][tx] = src[mb + (long)(r0+rr)*1024 + c0 + tx];
    __syncthreads();
    #pragma unroll
    for (int rr = ty; rr < 32; rr += 8)
        dst[mb + (long)(c0+rr)*1024 + r0 + tx] = f2bf(tile[tx][rr]);
}

// ---------------- flat fp32 -> bf16 convert ----------------------------
__global__ __launch_bounds__(256) void convert_bf16(
    const float* __restrict__ src, unsigned short* __restrict__ dst, long n)
{
    long i = ((long)blockIdx.x*256 + threadIdx.x)*4;
    if (i >= n) return;
    float4 v = *(const float4*)&src[i];
    ushort4 o = { f2bf(v.x), f2bf(v.y), f2bf(v.z), f2bf(v.w) };
    *(ushort4*)&dst[i] = o;
}

// ---------------- Residual + LayerNorm ---------------------------------
__global__ __launch_bounds__(256) void ln_residual(
    const float* __restrict__ X, const float* __restrict__ R,
    const float* __restrict__ gam, const float* __restrict__ bet,
    float* __restrict__ Y)
{
    const long row = blockIdx.x;
    const int t = threadIdx.x;
    float4 xv = *(const float4*)&X[row*DM + t*4];
    float4 rv = *(const float4*)&R[row*DM + t*4];
    float v0=xv.x+rv.x, v1=xv.y+rv.y, v2=xv.z+rv.z, v3=xv.w+rv.w;
    float s  = v0+v1+v2+v3;
    float s2 = v0*v0+v1*v1+v2*v2+v3*v3;
    #pragma unroll
    for (int off = 32; off > 0; off >>= 1) {
        s  += __shfl_down(s,  off, 64);
        s2 += __shfl_down(s2, off, 64);
    }
    __shared__ float red[8];
    __shared__ float mv[2];
    const int wid = t >> 6;
    if ((t & 63) == 0) { red[wid] = s; red[4+wid] = s2; }
    __syncthreads();
    if (t == 0) {
        float S  = red[0]+red[1]+red[2]+red[3];
        float S2 = red[4]+red[5]+red[6]+red[7];
        float mean = S * (1.f/DM);
        float var  = S2 * (1.f/DM) - mean*mean;
        mv[0] = mean; mv[1] = rsqrtf(var + 1e-5f);
    }
    __syncthreads();
    float mean = mv[0], inv = mv[1];
    float4 g4 = *(const float4*)&gam[t*4];
    float4 b4 = *(const float4*)&bet[t*4];
    float4 o4;
    o4.x = (v0-mean)*inv*g4.x + b4.x;
    o4.y = (v1-mean)*inv*g4.y + b4.y;
    o4.z = (v2-mean)*inv*g4.z + b4.z;
    o4.w = (v3-mean)*inv*g4.w + b4.w;
    *(float4*)&Y[row*DM + t*4] = o4;
}

// ---------------- Gate ---------------------------------------------------
__global__ __launch_bounds__(64) void gate_kernel(
    const float* __restrict__ X1, const float* __restrict__ gW,
    int* __restrict__ e1, int* __restrict__ e2,
    float* __restrict__ g1, float* __restrict__ g2,
    float* __restrict__ accum)
{
    const long row = blockIdx.x;
    const int l = threadIdx.x;
    const float* x = X1 + row*DM;
    float part[8];
    #pragma unroll
    for (int e = 0; e < 8; ++e) part[e] = 0.f;
    for (int i = l; i < DM; i += 64) {
        float xv = x[i];
        float4 w0 = *(const float4*)&gW[i*8];
        float4 w1 = *(const float4*)&gW[i*8+4];
        part[0]+=xv*w0.x; part[1]+=xv*w0.y; part[2]+=xv*w0.z; part[3]+=xv*w0.w;
        part[4]+=xv*w1.x; part[5]+=xv*w1.y; part[6]+=xv*w1.z; part[7]+=xv*w1.w;
    }
    #pragma unroll
    for (int e = 0; e < 8; ++e) {
        float v = part[e];
        #pragma unroll
        for (int off = 32; off > 0; off >>= 1) v += __shfl_down(v, off, 64);
        part[e] = v;
    }
    if (l == 0) {
        float mx = part[0];
        #pragma unroll
        for (int e = 1; e < 8; ++e) mx = fmaxf(mx, part[e]);
        float p[8]; float sum = 0.f;
        #pragma unroll
        for (int e = 0; e < 8; ++e) { p[e] = expf(part[e]-mx); sum += p[e]; }
        float lse = mx + logf(sum);
        float isum = 1.f/sum;
        #pragma unroll
        for (int e = 0; e < 8; ++e) p[e] *= isum;
        int b1 = 0;
        #pragma unroll
        for (int e = 1; e < 8; ++e) if (p[e] > p[b1]) b1 = e;
        int b2 = (b1 == 0) ? 1 : 0;
        #pragma unroll
        for (int e = 0; e < 8; ++e) if (e != b1 && e != b2 && p[e] > p[b2]) b2 = e;
        e1[row] = b1; e2[row] = b2; g1[row] = p[b1]; g2[row] = p[b2];
        atomicAdd(&accum[0], lse*lse);
        atomicAdd(&accum[9+b1], 1.0f);
        #pragma unroll
        for (int e = 0; e < 8; ++e) atomicAdd(&accum[1+e], p[e]);
    }
}

// ---------------- Routing scan ------------------------------------------
__global__ __launch_bounds__(64) void route_scan(
    const int* __restrict__ e1, const int* __restrict__ e2,
    const float* __restrict__ g2,
    int* __restrict__ pos1, int* __restrict__ keep1,
    int* __restrict__ pos2, int* __restrict__ keep2,
    int* __restrict__ slotmap)
{
    const int b = blockIdx.x;
    const int l = threadIdx.x;
    __shared__ int cnt[8];
    if (l < 8) cnt[l] = 0;
    __syncthreads();
    for (int slot = 0; slot < 2; ++slot) {
        const int* eArr = slot ? e2 : e1;
        for (int c = 0; c < SEQ/64; ++c) {
            const int tk = b*SEQ + c*64 + l;
            const int e = eArr[tk];
            const bool valid = slot ? (g2[tk] > 0.2f) : true;
            unsigned long long mymask = 0ull; int addmine = 0;
            #pragma unroll
            for (int ee = 0; ee < 8; ++ee) {
                unsigned long long bm = __ballot(valid && (e == ee));
                if (e == ee) mymask = bm;
                if (l == ee) addmine = (int)__popcll(bm);
            }
            const int p  = cnt[e] + (int)__popcll(mymask & ((1ull << l) - 1ull));
            const int kp = (valid && p < CAPE) ? 1 : 0;
            const int pc = p < CAPE ? p : (CAPE-1);
            if (slot == 0) { pos1[tk] = pc; keep1[tk] = kp; }
            else           { pos2[tk] = pc; keep2[tk] = kp; }
            if (kp) slotmap[(e*BATCH + b)*CAPE + pc] = tk;
            __syncthreads();
            if (l < 8) cnt[l] += addmine;
            __syncthreads();
        }
    }
}

// ---------------- Gather expert input -> bf16 ---------------------------
__global__ __launch_bounds__(256) void gather_expert(
    const float* __restrict__ X1, const int* __restrict__ slotmap,
    unsigned short* __restrict__ Ein, int e)
{
    const int slot = blockIdx.x;
    const int t = threadIdx.x;
    const int tok = slotmap[e*(BATCH*CAPE) + slot];
    float4 v4 = make_float4(0.f, 0.f, 0.f, 0.f);
    if (tok >= 0) v4 = *(const float4*)&X1[(long)tok*DM + t*4];
    ushort4 o = { f2bf(v4.x), f2bf(v4.y), f2bf(v4.z), f2bf(v4.w) };
    *(ushort4*)&Ein[(long)slot*DM + t*4] = o;
}

// ---------------- Scatter expert output ---------------------------------
__global__ __launch_bounds__(256) void scatter_combine(
    const float* __restrict__ Eout, float* __restrict__ Y,
    const int* __restrict__ e1, const int* __restrict__ pos1,
    const int* __restrict__ keep1, const float* __restrict__ g1,
    const int* __restrict__ e2, const int* __restrict__ pos2,
    const int* __restrict__ keep2, const float* __restrict__ g2,
    int e)
{
    const long row = blockIdx.x;
    const int b = (int)(row >> 10);
    const int t = threadIdx.x;
    float w; long src;
    if (e1[row] == e && keep1[row])      { w = g1[row]; src = ((long)b*CAPE + pos1[row])*DM; }
    else if (e2[row] == e && keep2[row]) { w = g2[row]; src = ((long)b*CAPE + pos2[row])*DM; }
    else return;
    float4 ev = *(const float4*)&Eout[src + t*4];
    float4 yv = *(float4*)&Y[row*DM + t*4];
    yv.x += w*ev.x; yv.y += w*ev.y; yv.z += w*ev.z; yv.w += w*ev.w;
    *(float4*)&Y[row*DM + t*4] = yv;
}

// ---------------- Loss scalars ------------------------------------------
__global__ void finalize_loss(const float* __restrict__ accum, float* __restrict__ out)
{
    float z = accum[0] * (1.0f/NTOK);
    float s = 0.f;
    for (int e = 0; e < 8; ++e)
        s += (accum[1+e] * (1.0f/NTOK)) * (accum[9+e] * (1.0f/NTOK));
    float bal = 0.01f * 8.0f * s;
    float zl  = 0.001f * z;
    out[OUTN]   = bal + zl;
    out[OUTN+1] = bal;
    out[OUTN+2] = zl;
}

extern "C" void kernel_launch(void* const* d_in, const int* in_sizes, int n_in,
                              void* d_out, int out_size, void* d_ws, size_t ws_size,
                              hipStream_t stream)
{
    (void)in_sizes; (void)n_in; (void)out_size; (void)ws_size;
    const float* x    = (const float*)d_in[0];
    const float* Wq   = (const float*)d_in[1];
    const float* Wk   = (const float*)d_in[2];
    const float* Wv   = (const float*)d_in[3];
    const float* Wo   = (const float*)d_in[4];
    const float* bq   = (const float*)d_in[5];
    const float* bk   = (const float*)d_in[6];
    const float* bv   = (const float*)d_in[7];
    const float* bo   = (const float*)d_in[8];
    const float* ln1g = (const float*)d_in[9];
    const float* ln1b = (const float*)d_in[10];
    const float* ln2g = (const float*)d_in[11];
    const float* ln2b = (const float*)d_in[12];
    const float* gW   = (const float*)d_in[13];
    const float* eWq  = (const float*)d_in[14];
    const float* eWk  = (const float*)d_in[15];
    const float* eWv  = (const float*)d_in[16];
    const float* eWo  = (const float*)d_in[17];
    float* out = (float*)d_out;

    char* ws = (char*)d_ws;
    const size_t MB = 1048576;
    const long MATE = 1024l*1024l;
    // layout (byte offsets):
    unsigned short* WTq  = (unsigned short*)(ws);            // 72 MB of weights
    unsigned short* WTk  = WTq + 1*MATE;
    unsigned short* WTv  = WTq + 2*MATE;
    unsigned short* WTo  = WTq + 3*MATE;
    unsigned short* eWTq = WTq + 4*MATE;
    unsigned short* eWTk = WTq + 12*MATE;
    unsigned short* eWTv = WTq + 20*MATE;
    unsigned short* eWTo = WTq + 28*MATE;
    unsigned short* xb = (unsigned short*)(ws + 72*MB);      // 16 MB x bf16
    unsigned short* ob = (unsigned short*)(ws + 88*MB);      // 16 MB attn-out bf16
    unsigned short* Qb = (unsigned short*)(ws + 104*MB);     // 16 MB
    unsigned short* Kb = (unsigned short*)(ws + 120*MB);     // 16 MB
    unsigned short* Vb = (unsigned short*)(ws + 136*MB);     // 16 MB
    float* Pf = (float*)(ws + 104*MB);                       // 32 MB, aliases Qb+Kb (dead after flash)
    float* x1 = (float*)(ws + 152*MB);                       // 32 MB
    float* yacc = (float*)(ws + 184*MB);                     // 32 MB
    int*   e1i   = (int*)(ws + 216*MB);
    int*   e2i   = e1i + NTOK;
    int*   pos1  = e1i + 2*NTOK;
    int*   pos2  = e1i + 3*NTOK;
    int*   keep1 = e1i + 4*NTOK;
    int*   keep2 = e1i + 5*NTOK;
    int*   slotmap = e1i + 6*NTOK;
    float* g1f   = (float*)(e1i + 6*NTOK + NE*BATCH*CAPE);
    float* g2f   = g1f + NTOK;
    float* accum = g2f + NTOK;
    // expert scratch aliases Pf region (dead after ln1) + part of Vb
    const long ECB = (long)BATCH*CAPE*DM;                    // 2,621,440 elems
    unsigned short* Einb = (unsigned short*)(ws + 104*MB);           // 5.25 MB
    unsigned short* eqb  = (unsigned short*)((char*)Einb + ECB*2);
    unsigned short* ekb  = (unsigned short*)((char*)Einb + ECB*4);
    unsigned short* evb  = (unsigned short*)((char*)Einb + ECB*6);
    unsigned short* eob  = (unsigned short*)((char*)Einb + ECB*8);
    float* eout = (float*)(ws + 104*MB);                     // aliases Einb+eqb (both dead by then)

    dim3 blk(256);
    dim3 tgrid(32, 32, 1), tgrid8(32, 32, 8);

    // ---- weight prep ----
    transpose_bf16<<<tgrid,  blk, 0, stream>>>(Wq,  WTq);
    transpose_bf16<<<tgrid,  blk, 0, stream>>>(Wk,  WTk);
    transpose_bf16<<<tgrid,  blk, 0, stream>>>(Wv,  WTv);
    transpose_bf16<<<tgrid,  blk, 0, stream>>>(Wo,  WTo);
    transpose_bf16<<<tgrid8, blk, 0, stream>>>(eWq, eWTq);
    transpose_bf16<<<tgrid8, blk, 0, stream>>>(eWk, eWTk);
    transpose_bf16<<<tgrid8, blk, 0, stream>>>(eWv, eWTv);
    transpose_bf16<<<tgrid8, blk, 0, stream>>>(eWo, eWTo);
    convert_bf16<<<NTOK, blk, 0, stream>>>(x, xb, OUTN);

    // ---- stage 1: MHA + LN1 ----
    dim3 gmain(DM/128, NTOK/128);
    gemm_bt<unsigned short><<<gmain, blk, 0, stream>>>(xb, WTq, bq, Qb, NTOK, DM, DM);
    gemm_bt<unsigned short><<<gmain, blk, 0, stream>>>(xb, WTk, bk, Kb, NTOK, DM, DM);
    gemm_bt<unsigned short><<<gmain, blk, 0, stream>>>(xb, WTv, bv, Vb, NTOK, DM, DM);
    flash_mfma<HDIM1><<<dim3(SEQ/64, NH1, BATCH), blk, 0, stream>>>(Qb, Kb, Vb, ob, SEQ, 0.125f);
    gemm_bt<float><<<gmain, blk, 0, stream>>>(ob, WTo, bo, Pf, NTOK, DM, DM);
    ln_residual<<<NTOK, blk, 0, stream>>>(x, Pf, ln1g, ln1b, x1);

    // ---- gate + routing ----
    hipMemsetAsync(accum, 0, 17*sizeof(float), stream);
    hipMemsetAsync(slotmap, 0xFF, NE*BATCH*CAPE*sizeof(int), stream);
    gate_kernel<<<NTOK, dim3(64), 0, stream>>>(x1, gW, e1i, e2i, g1f, g2f, accum);
    route_scan<<<BATCH, dim3(64), 0, stream>>>(e1i, e2i, g2f, pos1, keep1, pos2, keep2, slotmap);
    hipMemsetAsync(yacc, 0, OUTN*sizeof(float), stream);

    // ---- experts ----
    dim3 ge(DM/128, (BATCH*CAPE)/128);
    for (int e = 0; e < NE; ++e) {
        gather_expert<<<BATCH*CAPE, blk, 0, stream>>>(x1, slotmap, Einb, e);
        gemm_bt<unsigned short><<<ge, blk, 0, stream>>>(Einb, eWTq + (long)e*MATE, nullptr, eqb, BATCH*CAPE, DM, DM);
        gemm_bt<unsigned short><<<ge, blk, 0, stream>>>(Einb, eWTk + (long)e*MATE, nullptr, ekb, BATCH*CAPE, DM, DM);
        gemm_bt<unsigned short><<<ge, blk, 0, stream>>>(Einb, eWTv + (long)e*MATE, nullptr, evb, BATCH*CAPE, DM, DM);
        flash_mfma<HDIM2><<<dim3(CAPE/64, NH2, BATCH), blk, 0, stream>>>(eqb, ekb, evb, eob, CAPE, 0.088388347648318447f);
        gemm_bt<float><<<ge, blk, 0, stream>>>(eob, eWTo + (long)e*MATE, nullptr, eout, BATCH*CAPE, DM, DM);
        scatter_combine<<<NTOK, blk, 0, stream>>>(eout, yacc, e1i, pos1, keep1, g1f,
                                                  e2i, pos2, keep2, g2f, e);
    }

    // ---- final LN + losses ----
    ln_residual<<<NTOK, blk, 0, stream>>>(x1, yacc, ln2g, ln2b, out);
    finalize_loss<<<1, 1, 0, stream>>>(accum, out);
}

// Round 4
// 2120.110 us; speedup vs baseline: 4.5145x; 1.4002x over previous
//
#include <hip/hip_runtime.h>
#include <hip/hip_bf16.h>
#include <math.h>

#define DM    1024
#define NH1   16
#define HDIM1 64
#define NH2   8
#define HDIM2 128
#define NE    8
#define CAPE  320
#define BATCH 8
#define SEQ   1024
#define NTOK  (BATCH*SEQ)        /* 8192 */
#define OUTN  ((long)NTOK*DM)    /* 8388608 */

typedef short bf16x8 __attribute__((ext_vector_type(8)));
typedef float f32x4  __attribute__((ext_vector_type(4)));

__device__ __forceinline__ unsigned short f2bf(float f) {
    __hip_bfloat16 h = __float2bfloat16(f);
    return *reinterpret_cast<unsigned short*>(&h);
}

__device__ __forceinline__ void async16(const void* g, void* lds) {
    __builtin_amdgcn_global_load_lds(
        (const __attribute__((address_space(1))) unsigned int*)g,
        (__attribute__((address_space(3))) unsigned int*)lds, 16, 0, 0);
}

// ---------------- bf16 MFMA GEMM: C[M,N] = A[M,K]bf16 @ B^T[N,K]bf16 (+bias) ----
template<typename OT>
__global__ __launch_bounds__(256) void gemm_bt(
    const unsigned short* __restrict__ A, const unsigned short* __restrict__ Bt,
    const float* __restrict__ bias, OT* __restrict__ C,
    int M, int N, int K)
{
    __shared__ short ldsA[128*32];
    __shared__ short ldsB[128*32];
    const int t    = threadIdx.x;
    const int lane = t & 63, w = t >> 6;
    const int wr = w >> 1, wc = w & 1;
    const int m0 = blockIdx.y * 128, n0 = blockIdx.x * 128;
    const int lq = lane >> 4, lm = lane & 15;
    const int srow = w*16 + (lane >> 2);
    const int skc  = (lane & 3) * 8;

    f32x4 acc[4][4];
    #pragma unroll
    for (int i = 0; i < 4; ++i)
        #pragma unroll
        for (int j = 0; j < 4; ++j) acc[i][j] = (f32x4){0.f,0.f,0.f,0.f};

    for (int kb = 0; kb < K; kb += 32) {
        #pragma unroll
        for (int p = 0; p < 2; ++p) {
            async16(A  + (size_t)(m0 + srow + p*64)*K + kb + skc,
                    &ldsA[(w*16 + p*64)*32]);
            async16(Bt + (size_t)(n0 + srow + p*64)*K + kb + skc,
                    &ldsB[(w*16 + p*64)*32]);
        }
        __syncthreads();
        bf16x8 aF[4], bF[4];
        #pragma unroll
        for (int i = 0; i < 4; ++i)
            aF[i] = *(const bf16x8*)&ldsA[(wr*64 + i*16 + lm)*32 + lq*8];
        #pragma unroll
        for (int j = 0; j < 4; ++j)
            bF[j] = *(const bf16x8*)&ldsB[(wc*64 + j*16 + lm)*32 + lq*8];
        #pragma unroll
        for (int i = 0; i < 4; ++i)
            #pragma unroll
            for (int j = 0; j < 4; ++j)
                acc[i][j] = __builtin_amdgcn_mfma_f32_16x16x32_bf16(aF[i], bF[j], acc[i][j], 0, 0, 0);
        __syncthreads();
    }
    #pragma unroll
    for (int j = 0; j < 4; ++j) {
        const int gcol = n0 + wc*64 + j*16 + lm;
        const float badd = bias ? bias[gcol] : 0.f;
        #pragma unroll
        for (int i = 0; i < 4; ++i) {
            const int grow = m0 + wr*64 + i*16 + lq*4;
            #pragma unroll
            for (int r = 0; r < 4; ++r) {
                float v = acc[i][j][r] + badd;
                if constexpr (sizeof(OT) == 2)
                    C[(size_t)(grow + r)*N + gcol] = f2bf(v);
                else
                    C[(size_t)(grow + r)*N + gcol] = v;
            }
        }
    }
}

// ---------------- MFMA flash attention (bf16 in/out, fp32 softmax) ------
template<int HD>
__global__ __launch_bounds__(256) void flash_mfma(
    const unsigned short* __restrict__ Q, const unsigned short* __restrict__ K,
    const unsigned short* __restrict__ V, unsigned short* __restrict__ O,
    int rows, float scale)
{
    constexpr int QT = 64, KT = 64;
    constexpr int PADQ = HD + 8;
    constexpr int NKT = HD / 32;
    constexpr int NDT = HD / 16;
    constexpr int CG  = HD / 8;
    constexpr int RPR = 256 / CG;
    __shared__ __align__(16) unsigned short qs[QT * PADQ];
    __shared__ __align__(16) unsigned short ks[KT * PADQ];
    __shared__ __align__(16) unsigned short vt[HD * KT];
    __shared__ __align__(16) unsigned short pP[4][16 * 72];
    const int t = threadIdx.x, lane = t & 63, w = t >> 6;
    const int lm = lane & 15, quad = lane >> 4;
    const int q0 = blockIdx.x * QT;
    const long base = (long)blockIdx.z * rows * DM + (long)blockIdx.y * HD;
    const int srow = t / CG, scg = t % CG;

    #pragma unroll
    for (int r = 0; r < QT / RPR; ++r) {
        int row = srow + r * RPR;
        *(bf16x8*)&qs[row * PADQ + scg * 8] =
            *(const bf16x8*)&Q[base + (long)(q0 + row) * DM + scg * 8];
    }
    __syncthreads();
    bf16x8 aQ[NKT];
    #pragma unroll
    for (int kk = 0; kk < NKT; ++kk)
        aQ[kk] = *(const bf16x8*)&qs[(w * 16 + lm) * PADQ + kk * 32 + quad * 8];

    float m4[4], l4[4];
    #pragma unroll
    for (int r = 0; r < 4; ++r) { m4[r] = -1e30f; l4[r] = 0.f; }
    f32x4 aco[NDT];
    #pragma unroll
    for (int d = 0; d < NDT; ++d) aco[d] = (f32x4){0.f,0.f,0.f,0.f};

    for (int k0 = 0; k0 < rows; k0 += KT) {
        __syncthreads();
        #pragma unroll
        for (int r = 0; r < KT / RPR; ++r) {
            int row = srow + r * RPR;
            *(bf16x8*)&ks[row * PADQ + scg * 8] =
                *(const bf16x8*)&K[base + (long)(k0 + row) * DM + scg * 8];
            bf16x8 vv = *(const bf16x8*)&V[base + (long)(k0 + row) * DM + scg * 8];
            #pragma unroll
            for (int u = 0; u < 8; ++u) {
                int d = scg * 8 + u;
                vt[d * KT + ((row >> 3) ^ (d & 7)) * 8 + (row & 7)] = ((short*)&vv)[u];
            }
        }
        __syncthreads();
        f32x4 sc[4];
        #pragma unroll
        for (int n = 0; n < 4; ++n) {
            f32x4 c = (f32x4){0.f,0.f,0.f,0.f};
            #pragma unroll
            for (int kk = 0; kk < NKT; ++kk) {
                bf16x8 bK = *(const bf16x8*)&ks[(n * 16 + lm) * PADQ + kk * 32 + quad * 8];
                c = __builtin_amdgcn_mfma_f32_16x16x32_bf16(aQ[kk], bK, c, 0, 0, 0);
            }
            #pragma unroll
            for (int r = 0; r < 4; ++r) c[r] *= scale;
            sc[n] = c;
        }
        float alpha[4];
        #pragma unroll
        for (int r = 0; r < 4; ++r) {
            float mx = fmaxf(fmaxf(sc[0][r], sc[1][r]), fmaxf(sc[2][r], sc[3][r]));
            #pragma unroll
            for (int off = 1; off < 16; off <<= 1)
                mx = fmaxf(mx, __shfl_xor(mx, off, 64));
            float mnew = fmaxf(m4[r], mx);
            alpha[r] = __expf(m4[r] - mnew);
            m4[r] = mnew;
            float s = 0.f;
            #pragma unroll
            for (int n = 0; n < 4; ++n) {
                float p = __expf(sc[n][r] - mnew);
                sc[n][r] = p; s += p;
            }
            #pragma unroll
            for (int off = 1; off < 16; off <<= 1)
                s += __shfl_xor(s, off, 64);
            l4[r] = l4[r] * alpha[r] + s;
        }
        #pragma unroll
        for (int n = 0; n < 4; ++n)
            #pragma unroll
            for (int r = 0; r < 4; ++r)
                pP[w][(quad * 4 + r) * 72 + n * 16 + lm] = f2bf(sc[n][r]);
        #pragma unroll
        for (int d = 0; d < NDT; ++d)
            #pragma unroll
            for (int r = 0; r < 4; ++r) aco[d][r] *= alpha[r];
        #pragma unroll
        for (int d = 0; d < NDT; ++d) {
            #pragma unroll
            for (int kk = 0; kk < 2; ++kk) {
                bf16x8 aP = *(const bf16x8*)&pP[w][lm * 72 + kk * 32 + quad * 8];
                int dd = d * 16 + lm;
                int jb = kk * 4 + quad;
                bf16x8 bV = *(const bf16x8*)&vt[dd * KT + ((jb ^ (dd & 7)) * 8)];
                aco[d] = __builtin_amdgcn_mfma_f32_16x16x32_bf16(aP, bV, aco[d], 0, 0, 0);
            }
        }
    }
    #pragma unroll
    for (int r = 0; r < 4; ++r) l4[r] = 1.f / l4[r];
    #pragma unroll
    for (int d = 0; d < NDT; ++d)
        #pragma unroll
        for (int r = 0; r < 4; ++r)
            O[base + (long)(q0 + w * 16 + quad * 4 + r) * DM + d * 16 + lm] =
                f2bf(aco[d][r] * l4[r]);
}

// ---------------- weight transpose + fp32->bf16 -------------------------
__global__ __launch_bounds__(256) void transpose_bf16(
    const float* __restrict__ src, unsigned short* __restrict__ dst)
{
    __shared__ float tile[32][33];
    const long mb = (long)blockIdx.z * (1024l*1024l);
    const int tx = threadIdx.x & 31, ty = threadIdx.x >> 5;
    const int r0 = blockIdx.y * 32, c0 = blockIdx.x * 32;
    #pragma unroll
    for (int rr = ty; rr < 32; rr += 8)
        tile[rr][tx] = src[mb + (long)(r0+rr)*1024 + c0 + tx];
    __syncthreads();
    #pragma unroll
    for (int rr = ty; rr < 32; rr += 8)
        dst[mb + (long)(c0+rr)*1024 + r0 + tx] = f2bf(tile[tx][rr]);
}

// ---------------- flat fp32 -> bf16 convert ----------------------------
__global__ __launch_bounds__(256) void convert_bf16(
    const float* __restrict__ src, unsigned short* __restrict__ dst, long n)
{
    long i = ((long)blockIdx.x*256 + threadIdx.x)*4;
    if (i >= n) return;
    float4 v = *(const float4*)&src[i];
    ushort4 o = { f2bf(v.x), f2bf(v.y), f2bf(v.z), f2bf(v.w) };
    *(ushort4*)&dst[i] = o;
}

// ---------------- Residual + LayerNorm ---------------------------------
__global__ __launch_bounds__(256) void ln_residual(
    const float* __restrict__ X, const float* __restrict__ R,
    const float* __restrict__ gam, const float* __restrict__ bet,
    float* __restrict__ Y)
{
    const long row = blockIdx.x;
    const int t = threadIdx.x;
    float4 xv = *(const float4*)&X[row*DM + t*4];
    float4 rv = *(const float4*)&R[row*DM + t*4];
    float v0=xv.x+rv.x, v1=xv.y+rv.y, v2=xv.z+rv.z, v3=xv.w+rv.w;
    float s  = v0+v1+v2+v3;
    float s2 = v0*v0+v1*v1+v2*v2+v3*v3;
    #pragma unroll
    for (int off = 32; off > 0; off >>= 1) {
        s  += __shfl_down(s,  off, 64);
        s2 += __shfl_down(s2, off, 64);
    }
    __shared__ float red[8];
    __shared__ float mv[2];
    const int wid = t >> 6;
    if ((t & 63) == 0) { red[wid] = s; red[4+wid] = s2; }
    __syncthreads();
    if (t == 0) {
        float S  = red[0]+red[1]+red[2]+red[3];
        float S2 = red[4]+red[5]+red[6]+red[7];
        float mean = S * (1.f/DM);
        float var  = S2 * (1.f/DM) - mean*mean;
        mv[0] = mean; mv[1] = rsqrtf(var + 1e-5f);
    }
    __syncthreads();
    float mean = mv[0], inv = mv[1];
    float4 g4 = *(const float4*)&gam[t*4];
    float4 b4 = *(const float4*)&bet[t*4];
    float4 o4;
    o4.x = (v0-mean)*inv*g4.x + b4.x;
    o4.y = (v1-mean)*inv*g4.y + b4.y;
    o4.z = (v2-mean)*inv*g4.z + b4.z;
    o4.w = (v3-mean)*inv*g4.w + b4.w;
    *(float4*)&Y[row*DM + t*4] = o4;
}

// ---------------- Gate: 64 blocks x 4 waves, block-aggregated atomics ----
__global__ __launch_bounds__(256) void gate_kernel(
    const float* __restrict__ X1, const float* __restrict__ gW,
    int* __restrict__ e1, int* __restrict__ e2,
    float* __restrict__ g1, float* __restrict__ g2,
    float* __restrict__ accum)
{
    const int t = threadIdx.x, l = t & 63, w = t >> 6;
    const int gwave = blockIdx.x * 4 + w;     // 0..255
    float zacc = 0.f, pacc[8], facc[8];
    #pragma unroll
    for (int e = 0; e < 8; ++e) { pacc[e] = 0.f; facc[e] = 0.f; }

    for (int tok = gwave; tok < NTOK; tok += 256) {
        const float* xr = X1 + (long)tok*DM;
        float part[8];
        #pragma unroll
        for (int e = 0; e < 8; ++e) part[e] = 0.f;
        for (int i = l; i < DM; i += 64) {
            float xv = xr[i];
            float4 w0 = *(const float4*)&gW[i*8];
            float4 w1 = *(const float4*)&gW[i*8+4];
            part[0]+=xv*w0.x; part[1]+=xv*w0.y; part[2]+=xv*w0.z; part[3]+=xv*w0.w;
            part[4]+=xv*w1.x; part[5]+=xv*w1.y; part[6]+=xv*w1.z; part[7]+=xv*w1.w;
        }
        #pragma unroll
        for (int e = 0; e < 8; ++e) {
            float v = part[e];
            #pragma unroll
            for (int off = 32; off > 0; off >>= 1) v += __shfl_down(v, off, 64);
            part[e] = v;
        }
        if (l == 0) {
            float mx = part[0];
            #pragma unroll
            for (int e = 1; e < 8; ++e) mx = fmaxf(mx, part[e]);
            float p[8]; float sum = 0.f;
            #pragma unroll
            for (int e = 0; e < 8; ++e) { p[e] = __expf(part[e]-mx); sum += p[e]; }
            float lse = mx + __logf(sum);
            float isum = 1.f/sum;
            #pragma unroll
            for (int e = 0; e < 8; ++e) { p[e] *= isum; pacc[e] += p[e]; }
            int b1 = 0;
            #pragma unroll
            for (int e = 1; e < 8; ++e) if (p[e] > p[b1]) b1 = e;
            int b2 = (b1 == 0) ? 1 : 0;
            #pragma unroll
            for (int e = 0; e < 8; ++e) if (e != b1 && e != b2 && p[e] > p[b2]) b2 = e;
            e1[tok] = b1; e2[tok] = b2; g1[tok] = p[b1]; g2[tok] = p[b2];
            zacc += lse*lse;
            facc[b1] += 1.f;
        }
    }
    __shared__ float red[4][17];
    if (l == 0) {
        red[w][0] = zacc;
        #pragma unroll
        for (int e = 0; e < 8; ++e) { red[w][1+e] = pacc[e]; red[w][9+e] = facc[e]; }
    }
    __syncthreads();
    if (t < 17)
        atomicAdd(&accum[t], red[0][t] + red[1][t] + red[2][t] + red[3][t]);
}

// ---------------- Routing scan ------------------------------------------
__global__ __launch_bounds__(64) void route_scan(
    const int* __restrict__ e1, const int* __restrict__ e2,
    const float* __restrict__ g2,
    int* __restrict__ pos1, int* __restrict__ keep1,
    int* __restrict__ pos2, int* __restrict__ keep2,
    int* __restrict__ slotmap)
{
    const int b = blockIdx.x;
    const int l = threadIdx.x;
    __shared__ int cnt[8];
    if (l < 8) cnt[l] = 0;
    __syncthreads();
    for (int slot = 0; slot < 2; ++slot) {
        const int* eArr = slot ? e2 : e1;
        for (int c = 0; c < SEQ/64; ++c) {
            const int tk = b*SEQ + c*64 + l;
            const int e = eArr[tk];
            const bool valid = slot ? (g2[tk] > 0.2f) : true;
            unsigned long long mymask = 0ull; int addmine = 0;
            #pragma unroll
            for (int ee = 0; ee < 8; ++ee) {
                unsigned long long bm = __ballot(valid && (e == ee));
                if (e == ee) mymask = bm;
                if (l == ee) addmine = (int)__popcll(bm);
            }
            const int p  = cnt[e] + (int)__popcll(mymask & ((1ull << l) - 1ull));
            const int kp = (valid && p < CAPE) ? 1 : 0;
            const int pc = p < CAPE ? p : (CAPE-1);
            if (slot == 0) { pos1[tk] = pc; keep1[tk] = kp; }
            else           { pos2[tk] = pc; keep2[tk] = kp; }
            if (kp) slotmap[(e*BATCH + b)*CAPE + pc] = tk;
            __syncthreads();
            if (l < 8) cnt[l] += addmine;
            __syncthreads();
        }
    }
}

// ---------------- Gather expert input -> bf16 ---------------------------
__global__ __launch_bounds__(256) void gather_expert(
    const float* __restrict__ X1, const int* __restrict__ slotmap,
    unsigned short* __restrict__ Ein, int e)
{
    const int slot = blockIdx.x;
    const int t = threadIdx.x;
    const int tok = slotmap[e*(BATCH*CAPE) + slot];
    float4 v4 = make_float4(0.f, 0.f, 0.f, 0.f);
    if (tok >= 0) v4 = *(const float4*)&X1[(long)tok*DM + t*4];
    ushort4 o = { f2bf(v4.x), f2bf(v4.y), f2bf(v4.z), f2bf(v4.w) };
    *(ushort4*)&Ein[(long)slot*DM + t*4] = o;
}

// ---------------- Scatter expert output ---------------------------------
__global__ __launch_bounds__(256) void scatter_combine(
    const float* __restrict__ Eout, float* __restrict__ Y,
    const int* __restrict__ e1, const int* __restrict__ pos1,
    const int* __restrict__ keep1, const float* __restrict__ g1,
    const int* __restrict__ e2, const int* __restrict__ pos2,
    const int* __restrict__ keep2, const float* __restrict__ g2,
    int e)
{
    const long row = blockIdx.x;
    const int b = (int)(row >> 10);
    const int t = threadIdx.x;
    float w; long src;
    if (e1[row] == e && keep1[row])      { w = g1[row]; src = ((long)b*CAPE + pos1[row])*DM; }
    else if (e2[row] == e && keep2[row]) { w = g2[row]; src = ((long)b*CAPE + pos2[row])*DM; }
    else return;
    float4 ev = *(const float4*)&Eout[src + t*4];
    float4 yv = *(float4*)&Y[row*DM + t*4];
    yv.x += w*ev.x; yv.y += w*ev.y; yv.z += w*ev.z; yv.w += w*ev.w;
    *(float4*)&Y[row*DM + t*4] = yv;
}

// ---------------- Loss scalars ------------------------------------------
__global__ void finalize_loss(const float* __restrict__ accum, float* __restrict__ out)
{
    float z = accum[0] * (1.0f/NTOK);
    float s = 0.f;
    for (int e = 0; e < 8; ++e)
        s += (accum[1+e] * (1.0f/NTOK)) * (accum[9+e] * (1.0f/NTOK));
    float bal = 0.01f * 8.0f * s;
    float zl  = 0.001f * z;
    out[OUTN]   = bal + zl;
    out[OUTN+1] = bal;
    out[OUTN+2] = zl;
}

extern "C" void kernel_launch(void* const* d_in, const int* in_sizes, int n_in,
                              void* d_out, int out_size, void* d_ws, size_t ws_size,
                              hipStream_t stream)
{
    (void)in_sizes; (void)n_in; (void)out_size; (void)ws_size;
    const float* x    = (const float*)d_in[0];
    const float* Wq   = (const float*)d_in[1];
    const float* Wk   = (const float*)d_in[2];
    const float* Wv   = (const float*)d_in[3];
    const float* Wo   = (const float*)d_in[4];
    const float* bq   = (const float*)d_in[5];
    const float* bk   = (const float*)d_in[6];
    const float* bv   = (const float*)d_in[7];
    const float* bo   = (const float*)d_in[8];
    const float* ln1g = (const float*)d_in[9];
    const float* ln1b = (const float*)d_in[10];
    const float* ln2g = (const float*)d_in[11];
    const float* ln2b = (const float*)d_in[12];
    const float* gW   = (const float*)d_in[13];
    const float* eWq  = (const float*)d_in[14];
    const float* eWk  = (const float*)d_in[15];
    const float* eWv  = (const float*)d_in[16];
    const float* eWo  = (const float*)d_in[17];
    float* out = (float*)d_out;

    char* ws = (char*)d_ws;
    const size_t MB = 1048576;
    const long MATE = 1024l*1024l;
    unsigned short* WTq  = (unsigned short*)(ws);
    unsigned short* WTk  = WTq + 1*MATE;
    unsigned short* WTv  = WTq + 2*MATE;
    unsigned short* WTo  = WTq + 3*MATE;
    unsigned short* eWTq = WTq + 4*MATE;
    unsigned short* eWTk = WTq + 12*MATE;
    unsigned short* eWTv = WTq + 20*MATE;
    unsigned short* eWTo = WTq + 28*MATE;
    unsigned short* xb = (unsigned short*)(ws + 72*MB);
    unsigned short* ob = (unsigned short*)(ws + 88*MB);
    unsigned short* Qb = (unsigned short*)(ws + 104*MB);
    unsigned short* Kb = (unsigned short*)(ws + 120*MB);
    unsigned short* Vb = (unsigned short*)(ws + 136*MB);
    float* Pf = (float*)(ws + 104*MB);
    float* x1 = (float*)(ws + 152*MB);
    float* yacc = (float*)(ws + 184*MB);
    int*   e1i   = (int*)(ws + 216*MB);
    int*   e2i   = e1i + NTOK;
    int*   pos1  = e1i + 2*NTOK;
    int*   pos2  = e1i + 3*NTOK;
    int*   keep1 = e1i + 4*NTOK;
    int*   keep2 = e1i + 5*NTOK;
    int*   slotmap = e1i + 6*NTOK;
    float* g1f   = (float*)(e1i + 6*NTOK + NE*BATCH*CAPE);
    float* g2f   = g1f + NTOK;
    float* accum = g2f + NTOK;
    const long ECB = (long)BATCH*CAPE*DM;
    unsigned short* Einb = (unsigned short*)(ws + 104*MB);
    unsigned short* eqb  = (unsigned short*)((char*)Einb + ECB*2);
    unsigned short* ekb  = (unsigned short*)((char*)Einb + ECB*4);
    unsigned short* evb  = (unsigned short*)((char*)Einb + ECB*6);
    unsigned short* eob  = (unsigned short*)((char*)Einb + ECB*8);
    float* eout = (float*)(ws + 104*MB);

    dim3 blk(256);
    dim3 tgrid(32, 32, 1), tgrid8(32, 32, 8);

    // ---- weight prep ----
    transpose_bf16<<<tgrid,  blk, 0, stream>>>(Wq,  WTq);
    transpose_bf16<<<tgrid,  blk, 0, stream>>>(Wk,  WTk);
    transpose_bf16<<<tgrid,  blk, 0, stream>>>(Wv,  WTv);
    transpose_bf16<<<tgrid,  blk, 0, stream>>>(Wo,  WTo);
    transpose_bf16<<<tgrid8, blk, 0, stream>>>(eWq, eWTq);
    transpose_bf16<<<tgrid8, blk, 0, stream>>>(eWk, eWTk);
    transpose_bf16<<<tgrid8, blk, 0, stream>>>(eWv, eWTv);
    transpose_bf16<<<tgrid8, blk, 0, stream>>>(eWo, eWTo);
    convert_bf16<<<NTOK, blk, 0, stream>>>(x, xb, OUTN);

    // ---- stage 1: MHA + LN1 ----
    dim3 gmain(DM/128, NTOK/128);
    gemm_bt<unsigned short><<<gmain, blk, 0, stream>>>(xb, WTq, bq, Qb, NTOK, DM, DM);
    gemm_bt<unsigned short><<<gmain, blk, 0, stream>>>(xb, WTk, bk, Kb, NTOK, DM, DM);
    gemm_bt<unsigned short><<<gmain, blk, 0, stream>>>(xb, WTv, bv, Vb, NTOK, DM, DM);
    flash_mfma<HDIM1><<<dim3(SEQ/64, NH1, BATCH), blk, 0, stream>>>(Qb, Kb, Vb, ob, SEQ, 0.125f);
    gemm_bt<float><<<gmain, blk, 0, stream>>>(ob, WTo, bo, Pf, NTOK, DM, DM);
    ln_residual<<<NTOK, blk, 0, stream>>>(x, Pf, ln1g, ln1b, x1);

    // ---- gate + routing ----
    hipMemsetAsync(accum, 0, 17*sizeof(float), stream);
    hipMemsetAsync(slotmap, 0xFF, NE*BATCH*CAPE*sizeof(int), stream);
    gate_kernel<<<64, blk, 0, stream>>>(x1, gW, e1i, e2i, g1f, g2f, accum);
    route_scan<<<BATCH, dim3(64), 0, stream>>>(e1i, e2i, g2f, pos1, keep1, pos2, keep2, slotmap);
    hipMemsetAsync(yacc, 0, OUTN*sizeof(float), stream);

    // ---- experts ----
    dim3 ge(DM/128, (BATCH*CAPE)/128);
    for (int e = 0; e < NE; ++e) {
        gather_expert<<<BATCH*CAPE, blk, 0, stream>>>(x1, slotmap, Einb, e);
        gemm_bt<unsigned short><<<ge, blk, 0, stream>>>(Einb, eWTq + (long)e*MATE, nullptr, eqb, BATCH*CAPE, DM, DM);
        gemm_bt<unsigned short><<<ge, blk, 0, stream>>>(Einb, eWTk + (long)e*MATE, nullptr, ekb, BATCH*CAPE, DM, DM);
        gemm_bt<unsigned short><<<ge, blk, 0, stream>>>(Einb, eWTv + (long)e*MATE, nullptr, evb, BATCH*CAPE, DM, DM);
        flash_mfma<HDIM2><<<dim3(CAPE/64, NH2, BATCH), blk, 0, stream>>>(eqb, ekb, evb, eob, CAPE, 0.088388347648318447f);
        gemm_bt<float><<<ge, blk, 0, stream>>>(eob, eWTo + (long)e*MATE, nullptr, eout, BATCH*CAPE, DM, DM);
        scatter_combine<<<NTOK, blk, 0, stream>>>(eout, yacc, e1i, pos1, keep1, g1f,
                                                  e2i, pos2, keep2, g2f, e);
    }

    // ---- final LN + losses ----
    ln_residual<<<NTOK, blk, 0, stream>>>(x1, yacc, ln2g, ln2b, out);
    finalize_loss<<<1, 1, 0, stream>>>(accum, out);
}

// Round 5
// 1150.802 us; speedup vs baseline: 8.3170x; 1.8423x over previous
//
#include <hip/hip_runtime.h>
#include <hip/hip_bf16.h>
#include <math.h>

#define DM    1024
#define NH1   16
#define HDIM1 64
#define NH2   8
#define HDIM2 128
#define NE    8
#define CAPE  320
#define BATCH 8
#define SEQ   1024
#define NTOK  (BATCH*SEQ)        /* 8192 */
#define OUTN  ((long)NTOK*DM)    /* 8388608 */
#define ECB   ((long)BATCH*CAPE*DM)  /* 2,621,440 elems per expert */

typedef short bf16x8 __attribute__((ext_vector_type(8)));
typedef float f32x4  __attribute__((ext_vector_type(4)));

__device__ __forceinline__ unsigned short f2bf(float f) {
    __hip_bfloat16 h = __float2bfloat16(f);
    return *reinterpret_cast<unsigned short*>(&h);
}
__device__ __forceinline__ float bf2f(unsigned short u) {
    unsigned int x = ((unsigned int)u) << 16;
    return __builtin_bit_cast(float, x);
}

__device__ __forceinline__ void async16(const void* g, void* lds) {
    __builtin_amdgcn_global_load_lds(
        (const __attribute__((address_space(1))) unsigned int*)g,
        (__attribute__((address_space(3))) unsigned int*)lds, 16, 0, 0);
}

// ---------------- shared GEMM core: 128x128 tile, BK=32, 4 waves --------
// acc[i][j] accumulates C-tile (wr,wc wave grid). A[M,K], Bt[N,K] bf16.
__device__ __forceinline__ void gemm_core(
    const unsigned short* __restrict__ A, const unsigned short* __restrict__ Bt,
    int m0, int n0, int K, short* ldsA, short* ldsB, f32x4 (&acc)[4][4])
{
    const int t    = threadIdx.x;
    const int lane = t & 63, w = t >> 6;
    const int wr = w >> 1, wc = w & 1;
    const int lq = lane >> 4, lm = lane & 15;
    const int srow = w*16 + (lane >> 2);
    const int skc  = (lane & 3) * 8;
    for (int kb = 0; kb < K; kb += 32) {
        #pragma unroll
        for (int p = 0; p < 2; ++p) {
            async16(A  + (size_t)(m0 + srow + p*64)*K + kb + skc,
                    &ldsA[(w*16 + p*64)*32]);
            async16(Bt + (size_t)(n0 + srow + p*64)*K + kb + skc,
                    &ldsB[(w*16 + p*64)*32]);
        }
        __syncthreads();
        bf16x8 aF[4], bF[4];
        #pragma unroll
        for (int i = 0; i < 4; ++i)
            aF[i] = *(const bf16x8*)&ldsA[(wr*64 + i*16 + lm)*32 + lq*8];
        #pragma unroll
        for (int j = 0; j < 4; ++j)
            bF[j] = *(const bf16x8*)&ldsB[(wc*64 + j*16 + lm)*32 + lq*8];
        #pragma unroll
        for (int i = 0; i < 4; ++i)
            #pragma unroll
            for (int j = 0; j < 4; ++j)
                acc[i][j] = __builtin_amdgcn_mfma_f32_16x16x32_bf16(aF[i], bF[j], acc[i][j], 0, 0, 0);
        __syncthreads();
    }
}

// ---------------- plain GEMM (fp32 out, bias) — used for Wo projection ----
__global__ __launch_bounds__(256) void gemm_bt_f32(
    const unsigned short* __restrict__ A, const unsigned short* __restrict__ Bt,
    const float* __restrict__ bias, float* __restrict__ C, int N, int K)
{
    __shared__ short ldsA[128*32];
    __shared__ short ldsB[128*32];
    const int lane = threadIdx.x & 63, w = threadIdx.x >> 6;
    const int wr = w >> 1, wc = w & 1;
    const int lq = lane >> 4, lm = lane & 15;
    const int m0 = blockIdx.y * 128, n0 = blockIdx.x * 128;
    f32x4 acc[4][4];
    #pragma unroll
    for (int i = 0; i < 4; ++i)
        #pragma unroll
        for (int j = 0; j < 4; ++j) acc[i][j] = (f32x4){0.f,0.f,0.f,0.f};
    gemm_core(A, Bt, m0, n0, K, ldsA, ldsB, acc);
    #pragma unroll
    for (int j = 0; j < 4; ++j) {
        const int gcol = n0 + wc*64 + j*16 + lm;
        const float badd = bias ? bias[gcol] : 0.f;
        #pragma unroll
        for (int i = 0; i < 4; ++i) {
            const int grow = m0 + wr*64 + i*16 + lq*4;
            #pragma unroll
            for (int r = 0; r < 4; ++r)
                C[(size_t)(grow + r)*N + gcol] = acc[i][j][r] + badd;
        }
    }
}

// ---------------- fused main QKV GEMM: Bt = [WTq;WTk;WTv] (3072 x 1024) ----
// C base = Qb; Q/K/V outputs contiguous, each OUTN elems. bf16 out.
__global__ __launch_bounds__(256) void gemm_qkv(
    const unsigned short* __restrict__ A, const unsigned short* __restrict__ Bt,
    const float* __restrict__ bq, const float* __restrict__ bk, const float* __restrict__ bv,
    unsigned short* __restrict__ C)
{
    __shared__ short ldsA[128*32];
    __shared__ short ldsB[128*32];
    const int lane = threadIdx.x & 63, w = threadIdx.x >> 6;
    const int wr = w >> 1, wc = w & 1;
    const int lq = lane >> 4, lm = lane & 15;
    const int m0 = blockIdx.y * 128, n0g = blockIdx.x * 128;
    const int buf = n0g >> 10;
    const float* bias = (buf == 0) ? bq : (buf == 1) ? bk : bv;
    unsigned short* Cb = C + (size_t)buf * OUTN;
    f32x4 acc[4][4];
    #pragma unroll
    for (int i = 0; i < 4; ++i)
        #pragma unroll
        for (int j = 0; j < 4; ++j) acc[i][j] = (f32x4){0.f,0.f,0.f,0.f};
    gemm_core(A, Bt, m0, n0g, DM, ldsA, ldsB, acc);
    #pragma unroll
    for (int j = 0; j < 4; ++j) {
        const int gcol = (n0g & 1023) + wc*64 + j*16 + lm;
        const float badd = bias[gcol];
        #pragma unroll
        for (int i = 0; i < 4; ++i) {
            const int grow = m0 + wr*64 + i*16 + lq*4;
            #pragma unroll
            for (int r = 0; r < 4; ++r)
                Cb[(size_t)(grow + r)*DM + gcol] = f2bf(acc[i][j][r] + badd);
        }
    }
}

// ---------------- grouped expert QKV GEMM (2 experts per chunk) ----------
// grid (8, 40, 3): z selects {q,k,v}; y-block / 20 selects expert-in-chunk.
__global__ __launch_bounds__(256) void gemm_eqkv(
    const unsigned short* __restrict__ A,
    const unsigned short* __restrict__ eWTq, const unsigned short* __restrict__ eWTk,
    const unsigned short* __restrict__ eWTv,
    unsigned short* __restrict__ Cq, unsigned short* __restrict__ Ck,
    unsigned short* __restrict__ Cv, int ebase)
{
    __shared__ short ldsA[128*32];
    __shared__ short ldsB[128*32];
    const int lane = threadIdx.x & 63, w = threadIdx.x >> 6;
    const int wr = w >> 1, wc = w & 1;
    const int lq = lane >> 4, lm = lane & 15;
    const int z = blockIdx.z;
    const int eloc = blockIdx.y / 20;
    const unsigned short* Bt =
        ((z == 0) ? eWTq : (z == 1) ? eWTk : eWTv) + (size_t)(ebase + eloc) * (1024l*1024l);
    unsigned short* C = (z == 0) ? Cq : (z == 1) ? Ck : Cv;
    const int m0 = blockIdx.y * 128, n0 = blockIdx.x * 128;
    f32x4 acc[4][4];
    #pragma unroll
    for (int i = 0; i < 4; ++i)
        #pragma unroll
        for (int j = 0; j < 4; ++j) acc[i][j] = (f32x4){0.f,0.f,0.f,0.f};
    gemm_core(A, Bt, m0, n0, DM, ldsA, ldsB, acc);
    #pragma unroll
    for (int j = 0; j < 4; ++j) {
        const int gcol = n0 + wc*64 + j*16 + lm;
        #pragma unroll
        for (int i = 0; i < 4; ++i) {
            const int grow = m0 + wr*64 + i*16 + lq*4;
            #pragma unroll
            for (int r = 0; r < 4; ++r)
                C[(size_t)(grow + r)*DM + gcol] = f2bf(acc[i][j][r]);
        }
    }
}

// ---------------- grouped expert output GEMM (bf16 out) ------------------
__global__ __launch_bounds__(256) void gemm_eout(
    const unsigned short* __restrict__ A, const unsigned short* __restrict__ eWTo,
    unsigned short* __restrict__ C, int ebase)
{
    __shared__ short ldsA[128*32];
    __shared__ short ldsB[128*32];
    const int lane = threadIdx.x & 63, w = threadIdx.x >> 6;
    const int wr = w >> 1, wc = w & 1;
    const int lq = lane >> 4, lm = lane & 15;
    const int eloc = blockIdx.y / 20;
    const unsigned short* Bt = eWTo + (size_t)(ebase + eloc) * (1024l*1024l);
    const int m0 = blockIdx.y * 128, n0 = blockIdx.x * 128;
    f32x4 acc[4][4];
    #pragma unroll
    for (int i = 0; i < 4; ++i)
        #pragma unroll
        for (int j = 0; j < 4; ++j) acc[i][j] = (f32x4){0.f,0.f,0.f,0.f};
    gemm_core(A, Bt, m0, n0, DM, ldsA, ldsB, acc);
    #pragma unroll
    for (int j = 0; j < 4; ++j) {
        const int gcol = n0 + wc*64 + j*16 + lm;
        #pragma unroll
        for (int i = 0; i < 4; ++i) {
            const int grow = m0 + wr*64 + i*16 + lq*4;
            #pragma unroll
            for (int r = 0; r < 4; ++r)
                C[(size_t)(grow + r)*DM + gcol] = f2bf(acc[i][j][r]);
        }
    }
}

// ---------------- MFMA flash attention (bf16 in/out, fp32 softmax) ------
template<int HD>
__global__ __launch_bounds__(256) void flash_mfma(
    const unsigned short* __restrict__ Q, const unsigned short* __restrict__ K,
    const unsigned short* __restrict__ V, unsigned short* __restrict__ O,
    int rows, float scale)
{
    constexpr int QT = 64, KT = 64;
    constexpr int PADQ = HD + 8;
    constexpr int NKT = HD / 32;
    constexpr int NDT = HD / 16;
    constexpr int CG  = HD / 8;
    constexpr int RPR = 256 / CG;
    __shared__ __align__(16) unsigned short qs[QT * PADQ];
    __shared__ __align__(16) unsigned short ks[KT * PADQ];
    __shared__ __align__(16) unsigned short vt[HD * KT];
    __shared__ __align__(16) unsigned short pP[4][16 * 72];
    const int t = threadIdx.x, lane = t & 63, w = t >> 6;
    const int lm = lane & 15, quad = lane >> 4;
    const int q0 = blockIdx.x * QT;
    const long base = (long)blockIdx.z * rows * DM + (long)blockIdx.y * HD;
    const int srow = t / CG, scg = t % CG;

    #pragma unroll
    for (int r = 0; r < QT / RPR; ++r) {
        int row = srow + r * RPR;
        *(bf16x8*)&qs[row * PADQ + scg * 8] =
            *(const bf16x8*)&Q[base + (long)(q0 + row) * DM + scg * 8];
    }
    __syncthreads();
    bf16x8 aQ[NKT];
    #pragma unroll
    for (int kk = 0; kk < NKT; ++kk)
        aQ[kk] = *(const bf16x8*)&qs[(w * 16 + lm) * PADQ + kk * 32 + quad * 8];

    float m4[4], l4[4];
    #pragma unroll
    for (int r = 0; r < 4; ++r) { m4[r] = -1e30f; l4[r] = 0.f; }
    f32x4 aco[NDT];
    #pragma unroll
    for (int d = 0; d < NDT; ++d) aco[d] = (f32x4){0.f,0.f,0.f,0.f};

    for (int k0 = 0; k0 < rows; k0 += KT) {
        __syncthreads();
        #pragma unroll
        for (int r = 0; r < KT / RPR; ++r) {
            int row = srow + r * RPR;
            *(bf16x8*)&ks[row * PADQ + scg * 8] =
                *(const bf16x8*)&K[base + (long)(k0 + row) * DM + scg * 8];
            bf16x8 vv = *(const bf16x8*)&V[base + (long)(k0 + row) * DM + scg * 8];
            #pragma unroll
            for (int u = 0; u < 8; ++u) {
                int d = scg * 8 + u;
                vt[d * KT + ((row >> 3) ^ (d & 7)) * 8 + (row & 7)] = ((short*)&vv)[u];
            }
        }
        __syncthreads();
        f32x4 sc[4];
        #pragma unroll
        for (int n = 0; n < 4; ++n) {
            f32x4 c = (f32x4){0.f,0.f,0.f,0.f};
            #pragma unroll
            for (int kk = 0; kk < NKT; ++kk) {
                bf16x8 bK = *(const bf16x8*)&ks[(n * 16 + lm) * PADQ + kk * 32 + quad * 8];
                c = __builtin_amdgcn_mfma_f32_16x16x32_bf16(aQ[kk], bK, c, 0, 0, 0);
            }
            #pragma unroll
            for (int r = 0; r < 4; ++r) c[r] *= scale;
            sc[n] = c;
        }
        float alpha[4];
        #pragma unroll
        for (int r = 0; r < 4; ++r) {
            float mx = fmaxf(fmaxf(sc[0][r], sc[1][r]), fmaxf(sc[2][r], sc[3][r]));
            #pragma unroll
            for (int off = 1; off < 16; off <<= 1)
                mx = fmaxf(mx, __shfl_xor(mx, off, 64));
            float mnew = fmaxf(m4[r], mx);
            alpha[r] = __expf(m4[r] - mnew);
            m4[r] = mnew;
            float s = 0.f;
            #pragma unroll
            for (int n = 0; n < 4; ++n) {
                float p = __expf(sc[n][r] - mnew);
                sc[n][r] = p; s += p;
            }
            #pragma unroll
            for (int off = 1; off < 16; off <<= 1)
                s += __shfl_xor(s, off, 64);
            l4[r] = l4[r] * alpha[r] + s;
        }
        #pragma unroll
        for (int n = 0; n < 4; ++n)
            #pragma unroll
            for (int r = 0; r < 4; ++r)
                pP[w][(quad * 4 + r) * 72 + n * 16 + lm] = f2bf(sc[n][r]);
        #pragma unroll
        for (int d = 0; d < NDT; ++d)
            #pragma unroll
            for (int r = 0; r < 4; ++r) aco[d][r] *= alpha[r];
        #pragma unroll
        for (int d = 0; d < NDT; ++d) {
            #pragma unroll
            for (int kk = 0; kk < 2; ++kk) {
                bf16x8 aP = *(const bf16x8*)&pP[w][lm * 72 + kk * 32 + quad * 8];
                int dd = d * 16 + lm;
                int jb = kk * 4 + quad;
                bf16x8 bV = *(const bf16x8*)&vt[dd * KT + ((jb ^ (dd & 7)) * 8)];
                aco[d] = __builtin_amdgcn_mfma_f32_16x16x32_bf16(aP, bV, aco[d], 0, 0, 0);
            }
        }
    }
    #pragma unroll
    for (int r = 0; r < 4; ++r) l4[r] = 1.f / l4[r];
    #pragma unroll
    for (int d = 0; d < NDT; ++d)
        #pragma unroll
        for (int r = 0; r < 4; ++r)
            O[base + (long)(q0 + w * 16 + quad * 4 + r) * DM + d * 16 + lm] =
                f2bf(aco[d][r] * l4[r]);
}

// ---------------- weight transpose + fp32->bf16 -------------------------
__global__ __launch_bounds__(256) void transpose_bf16(
    const float* __restrict__ src, unsigned short* __restrict__ dst)
{
    __shared__ float tile[32][33];
    const long mb = (long)blockIdx.z * (1024l*1024l);
    const int tx = threadIdx.x & 31, ty = threadIdx.x >> 5;
    const int r0 = blockIdx.y * 32, c0 = blockIdx.x * 32;
    #pragma unroll
    for (int rr = ty; rr < 32; rr += 8)
        tile[rr][tx] = src[mb + (long)(r0+rr)*1024 + c0 + tx];
    __syncthreads();
    #pragma unroll
    for (int rr = ty; rr < 32; rr += 8)
        dst[mb + (long)(c0+rr)*1024 + r0 + tx] = f2bf(tile[tx][rr]);
}

// ---------------- flat fp32 -> bf16 convert ----------------------------
__global__ __launch_bounds__(256) void convert_bf16(
    const float* __restrict__ src, unsigned short* __restrict__ dst, long n)
{
    long i = ((long)blockIdx.x*256 + threadIdx.x)*4;
    if (i >= n) return;
    float4 v = *(const float4*)&src[i];
    ushort4 o = { f2bf(v.x), f2bf(v.y), f2bf(v.z), f2bf(v.w) };
    *(ushort4*)&dst[i] = o;
}

// ---------------- Residual + LayerNorm (fp32 out) -----------------------
__global__ __launch_bounds__(256) void ln_residual(
    const float* __restrict__ X, const float* __restrict__ R,
    const float* __restrict__ gam, const float* __restrict__ bet,
    float* __restrict__ Y)
{
    const long row = blockIdx.x;
    const int t = threadIdx.x;
    float4 xv = *(const float4*)&X[row*DM + t*4];
    float4 rv = *(const float4*)&R[row*DM + t*4];
    float v0=xv.x+rv.x, v1=xv.y+rv.y, v2=xv.z+rv.z, v3=xv.w+rv.w;
    float s  = v0+v1+v2+v3;
    float s2 = v0*v0+v1*v1+v2*v2+v3*v3;
    #pragma unroll
    for (int off = 32; off > 0; off >>= 1) {
        s  += __shfl_down(s,  off, 64);
        s2 += __shfl_down(s2, off, 64);
    }
    __shared__ float red[8];
    __shared__ float mv[2];
    const int wid = t >> 6;
    if ((t & 63) == 0) { red[wid] = s; red[4+wid] = s2; }
    __syncthreads();
    if (t == 0) {
        float S  = red[0]+red[1]+red[2]+red[3];
        float S2 = red[4]+red[5]+red[6]+red[7];
        float mean = S * (1.f/DM);
        float var  = S2 * (1.f/DM) - mean*mean;
        mv[0] = mean; mv[1] = rsqrtf(var + 1e-5f);
    }
    __syncthreads();
    float mean = mv[0], inv = mv[1];
    float4 g4 = *(const float4*)&gam[t*4];
    float4 b4 = *(const float4*)&bet[t*4];
    float4 o4;
    o4.x = (v0-mean)*inv*g4.x + b4.x;
    o4.y = (v1-mean)*inv*g4.y + b4.y;
    o4.z = (v2-mean)*inv*g4.z + b4.z;
    o4.w = (v3-mean)*inv*g4.w + b4.w;
    *(float4*)&Y[row*DM + t*4] = o4;
}

// ---------------- Combine (gather expert outs) + LN2 --------------------
__global__ __launch_bounds__(256) void combine_ln(
    const float* __restrict__ X1, const unsigned short* __restrict__ Eout,
    const int* __restrict__ e1, const int* __restrict__ pos1,
    const int* __restrict__ keep1, const float* __restrict__ g1,
    const int* __restrict__ e2, const int* __restrict__ pos2,
    const int* __restrict__ keep2, const float* __restrict__ g2,
    const float* __restrict__ gam, const float* __restrict__ bet,
    float* __restrict__ Y)
{
    const long row = blockIdx.x;
    const int b = (int)(row >> 10);
    const int t = threadIdx.x;
    float4 xv = *(const float4*)&X1[row*DM + t*4];
    float v0=xv.x, v1=xv.y, v2=xv.z, v3=xv.w;
    const float w1 = keep1[row] ? g1[row] : 0.f;
    const float w2 = keep2[row] ? g2[row] : 0.f;
    if (w1 != 0.f) {
        ushort4 u = *(const ushort4*)&Eout[(((size_t)e1[row]*BATCH + b)*CAPE + pos1[row])*DM + t*4];
        v0 += w1*bf2f(u.x); v1 += w1*bf2f(u.y); v2 += w1*bf2f(u.z); v3 += w1*bf2f(u.w);
    }
    if (w2 != 0.f) {
        ushort4 u = *(const ushort4*)&Eout[(((size_t)e2[row]*BATCH + b)*CAPE + pos2[row])*DM + t*4];
        v0 += w2*bf2f(u.x); v1 += w2*bf2f(u.y); v2 += w2*bf2f(u.z); v3 += w2*bf2f(u.w);
    }
    float s  = v0+v1+v2+v3;
    float s2 = v0*v0+v1*v1+v2*v2+v3*v3;
    #pragma unroll
    for (int off = 32; off > 0; off >>= 1) {
        s  += __shfl_down(s,  off, 64);
        s2 += __shfl_down(s2, off, 64);
    }
    __shared__ float red[8];
    __shared__ float mv[2];
    const int wid = t >> 6;
    if ((t & 63) == 0) { red[wid] = s; red[4+wid] = s2; }
    __syncthreads();
    if (t == 0) {
        float S  = red[0]+red[1]+red[2]+red[3];
        float S2 = red[4]+red[5]+red[6]+red[7];
        float mean = S * (1.f/DM);
        float var  = S2 * (1.f/DM) - mean*mean;
        mv[0] = mean; mv[1] = rsqrtf(var + 1e-5f);
    }
    __syncthreads();
    float mean = mv[0], inv = mv[1];
    float4 g4 = *(const float4*)&gam[t*4];
    float4 b4 = *(const float4*)&bet[t*4];
    float4 o4;
    o4.x = (v0-mean)*inv*g4.x + b4.x;
    o4.y = (v1-mean)*inv*g4.y + b4.y;
    o4.z = (v2-mean)*inv*g4.z + b4.z;
    o4.w = (v3-mean)*inv*g4.w + b4.w;
    *(float4*)&Y[row*DM + t*4] = o4;
}

// ---------------- Gate: 512 blocks x 4 waves, 1 wave per token ----------
__global__ __launch_bounds__(256) void gate_kernel(
    const float* __restrict__ X1, const float* __restrict__ gW,
    int* __restrict__ e1, int* __restrict__ e2,
    float* __restrict__ g1, float* __restrict__ g2,
    float* __restrict__ accum)
{
    const int t = threadIdx.x, l = t & 63, w = t >> 6;
    const int gwave = blockIdx.x * 4 + w;     // 0..2047
    float zacc = 0.f, pacc[8], facc[8];
    #pragma unroll
    for (int e = 0; e < 8; ++e) { pacc[e] = 0.f; facc[e] = 0.f; }

    for (int tok = gwave; tok < NTOK; tok += 2048) {
        const float* xr = X1 + (long)tok*DM;
        float part[8];
        #pragma unroll
        for (int e = 0; e < 8; ++e) part[e] = 0.f;
        #pragma unroll
        for (int pass = 0; pass < 4; ++pass) {
            const int i0 = pass*256 + l*4;
            float4 xv = *(const float4*)&xr[i0];
            const float xs[4] = {xv.x, xv.y, xv.z, xv.w};
            #pragma unroll
            for (int u = 0; u < 4; ++u) {
                float4 w0 = *(const float4*)&gW[(i0+u)*8];
                float4 w1 = *(const float4*)&gW[(i0+u)*8+4];
                part[0]+=xs[u]*w0.x; part[1]+=xs[u]*w0.y; part[2]+=xs[u]*w0.z; part[3]+=xs[u]*w0.w;
                part[4]+=xs[u]*w1.x; part[5]+=xs[u]*w1.y; part[6]+=xs[u]*w1.z; part[7]+=xs[u]*w1.w;
            }
        }
        #pragma unroll
        for (int e = 0; e < 8; ++e) {
            float v = part[e];
            #pragma unroll
            for (int off = 32; off > 0; off >>= 1) v += __shfl_down(v, off, 64);
            part[e] = v;
        }
        if (l == 0) {
            float mx = part[0];
            #pragma unroll
            for (int e = 1; e < 8; ++e) mx = fmaxf(mx, part[e]);
            float p[8]; float sum = 0.f;
            #pragma unroll
            for (int e = 0; e < 8; ++e) { p[e] = __expf(part[e]-mx); sum += p[e]; }
            float lse = mx + __logf(sum);
            float isum = 1.f/sum;
            #pragma unroll
            for (int e = 0; e < 8; ++e) { p[e] *= isum; pacc[e] += p[e]; }
            int b1 = 0;
            #pragma unroll
            for (int e = 1; e < 8; ++e) if (p[e] > p[b1]) b1 = e;
            int b2 = (b1 == 0) ? 1 : 0;
            #pragma unroll
            for (int e = 0; e < 8; ++e) if (e != b1 && e != b2 && p[e] > p[b2]) b2 = e;
            e1[tok] = b1; e2[tok] = b2; g1[tok] = p[b1]; g2[tok] = p[b2];
            zacc += lse*lse;
            facc[b1] += 1.f;
        }
    }
    __shared__ float red[4][17];
    if (l == 0) {
        red[w][0] = zacc;
        #pragma unroll
        for (int e = 0; e < 8; ++e) { red[w][1+e] = pacc[e]; red[w][9+e] = facc[e]; }
    }
    __syncthreads();
    if (t < 17)
        atomicAdd(&accum[t], red[0][t] + red[1][t] + red[2][t] + red[3][t]);
}

// ---------------- Routing scan ------------------------------------------
__global__ __launch_bounds__(64) void route_scan(
    const int* __restrict__ e1, const int* __restrict__ e2,
    const float* __restrict__ g2,
    int* __restrict__ pos1, int* __restrict__ keep1,
    int* __restrict__ pos2, int* __restrict__ keep2,
    int* __restrict__ slotmap)
{
    const int b = blockIdx.x;
    const int l = threadIdx.x;
    __shared__ int cnt[8];
    if (l < 8) cnt[l] = 0;
    __syncthreads();
    for (int slot = 0; slot < 2; ++slot) {
        const int* eArr = slot ? e2 : e1;
        for (int c = 0; c < SEQ/64; ++c) {
            const int tk = b*SEQ + c*64 + l;
            const int e = eArr[tk];
            const bool valid = slot ? (g2[tk] > 0.2f) : true;
            unsigned long long mymask = 0ull; int addmine = 0;
            #pragma unroll
            for (int ee = 0; ee < 8; ++ee) {
                unsigned long long bm = __ballot(valid && (e == ee));
                if (e == ee) mymask = bm;
                if (l == ee) addmine = (int)__popcll(bm);
            }
            const int p  = cnt[e] + (int)__popcll(mymask & ((1ull << l) - 1ull));
            const int kp = (valid && p < CAPE) ? 1 : 0;
            const int pc = p < CAPE ? p : (CAPE-1);
            if (slot == 0) { pos1[tk] = pc; keep1[tk] = kp; }
            else           { pos2[tk] = pc; keep2[tk] = kp; }
            if (kp) slotmap[(e*BATCH + b)*CAPE + pc] = tk;
            __syncthreads();
            if (l < 8) cnt[l] += addmine;
            __syncthreads();
        }
    }
}

// ---------------- Gather expert inputs for a 2-expert chunk -------------
__global__ __launch_bounds__(256) void gather_chunk(
    const float* __restrict__ X1, const int* __restrict__ slotmap,
    unsigned short* __restrict__ Ein, int ebase)
{
    const int slot = blockIdx.x;              // [eloc][b][p], eloc in 0..1
    const int t = threadIdx.x;
    const int tok = slotmap[ebase*(BATCH*CAPE) + slot];
    float4 v4 = make_float4(0.f, 0.f, 0.f, 0.f);
    if (tok >= 0) v4 = *(const float4*)&X1[(long)tok*DM + t*4];
    ushort4 o = { f2bf(v4.x), f2bf(v4.y), f2bf(v4.z), f2bf(v4.w) };
    *(ushort4*)&Ein[(long)slot*DM + t*4] = o;
}

// ---------------- Loss scalars ------------------------------------------
__global__ void finalize_loss(const float* __restrict__ accum, float* __restrict__ out)
{
    float z = accum[0] * (1.0f/NTOK);
    float s = 0.f;
    for (int e = 0; e < 8; ++e)
        s += (accum[1+e] * (1.0f/NTOK)) * (accum[9+e] * (1.0f/NTOK));
    float bal = 0.01f * 8.0f * s;
    float zl  = 0.001f * z;
    out[OUTN]   = bal + zl;
    out[OUTN+1] = bal;
    out[OUTN+2] = zl;
}

extern "C" void kernel_launch(void* const* d_in, const int* in_sizes, int n_in,
                              void* d_out, int out_size, void* d_ws, size_t ws_size,
                              hipStream_t stream)
{
    (void)in_sizes; (void)n_in; (void)out_size; (void)ws_size;
    const float* x    = (const float*)d_in[0];
    const float* Wq   = (const float*)d_in[1];
    const float* Wk   = (const float*)d_in[2];
    const float* Wv   = (const float*)d_in[3];
    const float* Wo   = (const float*)d_in[4];
    const float* bq   = (const float*)d_in[5];
    const float* bk   = (const float*)d_in[6];
    const float* bv   = (const float*)d_in[7];
    const float* bo   = (const float*)d_in[8];
    const float* ln1g = (const float*)d_in[9];
    const float* ln1b = (const float*)d_in[10];
    const float* ln2g = (const float*)d_in[11];
    const float* ln2b = (const float*)d_in[12];
    const float* gW   = (const float*)d_in[13];
    const float* eWq  = (const float*)d_in[14];
    const float* eWk  = (const float*)d_in[15];
    const float* eWv  = (const float*)d_in[16];
    const float* eWo  = (const float*)d_in[17];
    float* out = (float*)d_out;

    char* ws = (char*)d_ws;
    const size_t MB = 1048576;
    const long MATE = 1024l*1024l;
    // ---- layout ----
    // 0-72 MB: bf16 transposed weights
    unsigned short* WTq  = (unsigned short*)(ws);           // 3 contiguous for fused QKV
    unsigned short* WTk  = WTq + 1*MATE;
    unsigned short* WTv  = WTq + 2*MATE;
    unsigned short* WTo  = WTq + 3*MATE;
    unsigned short* eWTq = WTq + 4*MATE;
    unsigned short* eWTk = WTq + 12*MATE;
    unsigned short* eWTv = WTq + 20*MATE;
    unsigned short* eWTo = WTq + 28*MATE;
    // 72-74 MB: routing/meta
    int*   e1i   = (int*)(ws + 72*MB);
    int*   e2i   = e1i + NTOK;
    int*   pos1  = e1i + 2*NTOK;
    int*   pos2  = e1i + 3*NTOK;
    int*   keep1 = e1i + 4*NTOK;
    int*   keep2 = e1i + 5*NTOK;
    int*   slotmap = e1i + 6*NTOK;                          // 20480 ints
    float* g1f   = (float*)(e1i + 6*NTOK + NE*BATCH*CAPE);
    float* g2f   = g1f + NTOK;
    float* accum = g2f + NTOK;                              // 17 floats
    // stage-1 buffers
    unsigned short* xb = (unsigned short*)(ws + 74*MB);     // 16 MB
    unsigned short* ob = (unsigned short*)(ws + 90*MB);     // 16 MB
    unsigned short* Qb = (unsigned short*)(ws + 106*MB);    // Q/K/V contiguous 48 MB
    float* Pf = (float*)(ws + 106*MB);                      // fp32 Wo out (aliases Q/K)
    float* x1 = (float*)(ws + 154*MB);                      // 32 MB
    // expert phase (stage-1 region 74-154 dead after ln1)
    unsigned short* eoutAll = (unsigned short*)(ws + 74*MB);   // 40 MB: [8][8][320][1024]
    unsigned short* Einb = (unsigned short*)(ws + 114*MB);     // 10 MB (2-expert chunk)
    unsigned short* eqb  = (unsigned short*)(ws + 124*MB);
    unsigned short* ekb  = (unsigned short*)(ws + 134*MB);
    unsigned short* evb  = (unsigned short*)(ws + 144*MB);
    unsigned short* eob  = Einb;                               // alias (Ein dead after qkv)

    dim3 blk(256);
    dim3 tgrid(32, 32, 1), tgrid8(32, 32, 8);

    // ---- weight prep ----
    transpose_bf16<<<tgrid,  blk, 0, stream>>>(Wq,  WTq);
    transpose_bf16<<<tgrid,  blk, 0, stream>>>(Wk,  WTk);
    transpose_bf16<<<tgrid,  blk, 0, stream>>>(Wv,  WTv);
    transpose_bf16<<<tgrid,  blk, 0, stream>>>(Wo,  WTo);
    transpose_bf16<<<tgrid8, blk, 0, stream>>>(eWq, eWTq);
    transpose_bf16<<<tgrid8, blk, 0, stream>>>(eWk, eWTk);
    transpose_bf16<<<tgrid8, blk, 0, stream>>>(eWv, eWTv);
    transpose_bf16<<<tgrid8, blk, 0, stream>>>(eWo, eWTo);
    convert_bf16<<<NTOK, blk, 0, stream>>>(x, xb, OUTN);

    // ---- stage 1: MHA + LN1 ----
    gemm_qkv<<<dim3(3*DM/128, NTOK/128), blk, 0, stream>>>(xb, WTq, bq, bk, bv, Qb);
    flash_mfma<HDIM1><<<dim3(SEQ/64, NH1, BATCH), blk, 0, stream>>>(
        Qb, Qb + OUTN, Qb + 2*OUTN, ob, SEQ, 0.125f);
    gemm_bt_f32<<<dim3(DM/128, NTOK/128), blk, 0, stream>>>(ob, WTo, bo, Pf, DM, DM);
    ln_residual<<<NTOK, blk, 0, stream>>>(x, Pf, ln1g, ln1b, x1);

    // ---- gate + routing ----
    hipMemsetAsync(accum, 0, 17*sizeof(float), stream);
    hipMemsetAsync(slotmap, 0xFF, NE*BATCH*CAPE*sizeof(int), stream);
    gate_kernel<<<512, blk, 0, stream>>>(x1, gW, e1i, e2i, g1f, g2f, accum);
    route_scan<<<BATCH, dim3(64), 0, stream>>>(e1i, e2i, g2f, pos1, keep1, pos2, keep2, slotmap);

    // ---- experts: 4 chunks of 2 ----
    for (int c = 0; c < 4; ++c) {
        const int ebase = c*2;
        gather_chunk<<<2*BATCH*CAPE, blk, 0, stream>>>(x1, slotmap, Einb, ebase);
        gemm_eqkv<<<dim3(DM/128, 2*BATCH*CAPE/128, 3), blk, 0, stream>>>(
            Einb, eWTq, eWTk, eWTv, eqb, ekb, evb, ebase);
        flash_mfma<HDIM2><<<dim3(CAPE/64, NH2, 2*BATCH), blk, 0, stream>>>(
            eqb, ekb, evb, eob, CAPE, 0.088388347648318447f);
        gemm_eout<<<dim3(DM/128, 2*BATCH*CAPE/128), blk, 0, stream>>>(
            eob, eWTo, eoutAll + (size_t)ebase*ECB, ebase);
    }

    // ---- combine + final LN + losses ----
    combine_ln<<<NTOK, blk, 0, stream>>>(x1, eoutAll, e1i, pos1, keep1, g1f,
                                         e2i, pos2, keep2, g2f, ln2g, ln2b, out);
    finalize_loss<<<1, 1, 0, stream>>>(accum, out);
}